// Round 1
// baseline (652.985 us; speedup 1.0000x reference)
//
#include <hip/hip_runtime.h>

#define TSEQ  4096
#define NBATCH 4
#define CDIM  2048
#define DH    128

typedef __bf16 bf16x8 __attribute__((ext_vector_type(8)));
typedef float  f32x4  __attribute__((ext_vector_type(4)));
typedef unsigned short u16x8 __attribute__((ext_vector_type(8)));

__device__ __forceinline__ unsigned short f2bf(float f) {
  union { float f; unsigned u; } v; v.f = f;
  unsigned r = (v.u + 0x7FFFu + ((v.u >> 16) & 1u)) >> 16;
  return (unsigned short)r;
}

__device__ __forceinline__ bf16x8 ld_bf8(const unsigned short* p) {
  return __builtin_bit_cast(bf16x8, *(const u16x8*)p);
}

// ---------------- prep: w_q fp32 -> bf16 ----------------
__global__ void k_wconv(const float* __restrict__ w, unsigned short* __restrict__ wbf) {
  int i = blockIdx.x * 256 + threadIdx.x;          // 65536 threads, 4 elems each
  const float4 v = *(const float4*)(w + (size_t)i * 4);
  unsigned lo = (unsigned)f2bf(v.x) | ((unsigned)f2bf(v.y) << 16);
  unsigned hi = (unsigned)f2bf(v.z) | ((unsigned)f2bf(v.w) << 16);
  uint2 o; o.x = lo; o.y = hi;
  *(uint2*)(wbf + (size_t)i * 4) = o;
}

// ---------------- prep: rope(key) -> bf16 k_rot ----------------
__global__ void k_ropek(const float* __restrict__ key, unsigned short* __restrict__ krot) {
  int g = blockIdx.x * 256 + threadIdx.x;          // pair index, NBATCH*TSEQ*64 total
  int p = g & 63;
  int row = g >> 6;                                // b*TSEQ + t
  int t = row & (TSEQ - 1);
  const float2 kv = *(const float2*)(key + (size_t)row * DH + 2 * p);
  float inv = powf(10000.0f, -(float)p / 64.0f);
  float ang = (float)t * inv;
  float s, c; sincosf(ang, &s, &c);
  float o1 = kv.x * c - kv.y * s;
  float o2 = kv.x * s + kv.y * c;
  unsigned pk = (unsigned)f2bf(o1) | ((unsigned)f2bf(o2) << 16);
  *(unsigned*)(krot + (size_t)row * DH + 2 * p) = pk;
}

// ---------------- prep: transpose value -> bf16 v_t[b][d][t] ----------------
__global__ void k_vt(const float* __restrict__ v, unsigned short* __restrict__ vt) {
  __shared__ unsigned short S[128 * 66];
  int bid = blockIdx.x;                  // NBATCH * (TSEQ/64)
  int b = bid >> 6;
  int t0 = (bid & 63) * 64;
  int tid = threadIdx.x;
  int d = (tid & 31) * 4;
  int tl0 = tid >> 5;                    // 0..7
#pragma unroll
  for (int i = 0; i < 8; ++i) {
    int tl = tl0 + i * 8;
    const float4 val = *(const float4*)(v + ((size_t)(b * TSEQ + t0 + tl)) * DH + d);
    S[(d + 0) * 66 + tl] = f2bf(val.x);
    S[(d + 1) * 66 + tl] = f2bf(val.y);
    S[(d + 2) * 66 + tl] = f2bf(val.z);
    S[(d + 3) * 66 + tl] = f2bf(val.w);
  }
  __syncthreads();
#pragma unroll
  for (int i = 0; i < 16; ++i) {
    int idx = tid + i * 256;             // 4096 dwords
    int dd = idx >> 5;
    int tw = (idx & 31) * 2;
    unsigned lo = S[dd * 66 + tw];
    unsigned hi = S[dd * 66 + tw + 1];
    *(unsigned*)(vt + ((size_t)(b * DH + dd)) * TSEQ + t0 + tw) = lo | (hi << 16);
  }
}

// ---------------- q projection GEMM (bf16 MFMA) + fused RoPE + scale ----------------
__global__ __launch_bounds__(256) void k_qproj(const float* __restrict__ x,
                                               const unsigned short* __restrict__ wbf,
                                               unsigned short* __restrict__ qrot) {
  int bid = blockIdx.x;                  // 256 blocks, 64 rows each
  int tid = threadIdx.x;
  int w = tid >> 6;
  int lane = tid & 63;
  int l15 = lane & 15;
  int quad = lane >> 4;

  int arow = bid * 64 + w * 16 + l15;    // A-fragment row (token)
  const float* xrow = x + (size_t)arow * CDIM;

  f32x4 acc[8];
#pragma unroll
  for (int i = 0; i < 8; ++i) acc[i] = (f32x4){0.f, 0.f, 0.f, 0.f};

  for (int it = 0; it < CDIM / 32; ++it) {
    int k0 = it * 32 + quad * 8;
    float4 a0 = *(const float4*)(xrow + k0);
    float4 a1 = *(const float4*)(xrow + k0 + 4);
    u16x8 au;
    au[0] = f2bf(a0.x); au[1] = f2bf(a0.y); au[2] = f2bf(a0.z); au[3] = f2bf(a0.w);
    au[4] = f2bf(a1.x); au[5] = f2bf(a1.y); au[6] = f2bf(a1.z); au[7] = f2bf(a1.w);
    bf16x8 af = __builtin_bit_cast(bf16x8, au);
#pragma unroll
    for (int nt = 0; nt < 8; ++nt) {
      bf16x8 bf = ld_bf8(wbf + (size_t)(nt * 16 + l15) * CDIM + k0);
      acc[nt] = __builtin_amdgcn_mfma_f32_16x16x32_bf16(af, bf, acc[nt], 0, 0, 0);
    }
  }

  // epilogue: RoPE (interleaved pairs across even/odd lanes) + 1/sqrt(D) scale
  const float scale = 0.08838834764831845f;  // 128^-0.5
#pragma unroll
  for (int nt = 0; nt < 8; ++nt) {
    int dcol = nt * 16 + l15;
    int p = dcol >> 1;
    float inv = powf(10000.0f, -(float)p / 64.0f);
#pragma unroll
    for (int r = 0; r < 4; ++r) {
      int m = bid * 64 + w * 16 + quad * 4 + r;   // output token row
      int t = m & (TSEQ - 1);
      float val = acc[nt][r];
      float partner = __shfl_xor(val, 1, 64);
      float ang = (float)t * inv;
      float s, c; sincosf(ang, &s, &c);
      float o = (lane & 1) ? (val * c + partner * s) : (val * c - partner * s);
      qrot[(size_t)m * DH + dcol] = f2bf(o * scale);
    }
  }
}

// ---------------- causal flash attention ----------------
__global__ __launch_bounds__(256) void k_attn(const unsigned short* __restrict__ qrot,
                                              const unsigned short* __restrict__ krot,
                                              const unsigned short* __restrict__ vt,
                                              float* __restrict__ out) {
  __shared__ unsigned short Pl[4 * 16 * 72];   // per-wave P tile, 16 rows stride 72
  int bid = blockIdx.x;                  // b*64 + qt
  int b = bid >> 6;
  int qt = bid & 63;
  int tid = threadIdx.x;
  int w = tid >> 6;
  int lane = tid & 63;
  int l15 = lane & 15;
  int quad = lane >> 4;
  unsigned short* pw = Pl + w * 16 * 72;

  // Q fragments stay in registers for the whole K loop
  bf16x8 qf[4];
  {
    const unsigned short* qb = qrot + ((size_t)(b * TSEQ + qt * 64 + w * 16 + l15)) * DH + quad * 8;
#pragma unroll
    for (int c = 0; c < 4; ++c) qf[c] = ld_bf8(qb + c * 32);
  }

  f32x4 o_acc[8];
#pragma unroll
  for (int i = 0; i < 8; ++i) o_acc[i] = (f32x4){0.f, 0.f, 0.f, 0.f};
  float m_st[4], l_st[4];
#pragma unroll
  for (int r = 0; r < 4; ++r) { m_st[r] = -INFINITY; l_st[r] = 0.f; }

  const unsigned short* kb = krot + (size_t)b * TSEQ * DH;
  const unsigned short* vb = vt + (size_t)b * DH * TSEQ;

  for (int kt = 0; kt <= qt; ++kt) {
    // S = Q @ K^T  (16 q-rows x 64 keys per wave)
    f32x4 s[4];
#pragma unroll
    for (int nt = 0; nt < 4; ++nt) {
      s[nt] = (f32x4){0.f, 0.f, 0.f, 0.f};
      const unsigned short* kr = kb + (size_t)(kt * 64 + nt * 16 + l15) * DH + quad * 8;
#pragma unroll
      for (int c = 0; c < 4; ++c) {
        bf16x8 bf = ld_bf8(kr + c * 32);
        s[nt] = __builtin_amdgcn_mfma_f32_16x16x32_bf16(qf[c], bf, s[nt], 0, 0, 0);
      }
    }
    // causal mask on diagonal tile
    if (kt == qt) {
#pragma unroll
      for (int nt = 0; nt < 4; ++nt)
#pragma unroll
        for (int r = 0; r < 4; ++r) {
          int key_l = nt * 16 + l15;
          int q_l = w * 16 + quad * 4 + r;
          if (key_l > q_l) s[nt][r] = -INFINITY;
        }
    }
    // online softmax (row r lives in the 16 lanes of this quad)
    float alpha[4];
#pragma unroll
    for (int r = 0; r < 4; ++r) {
      float rm = fmaxf(fmaxf(s[0][r], s[1][r]), fmaxf(s[2][r], s[3][r]));
      rm = fmaxf(rm, __shfl_xor(rm, 1, 16));
      rm = fmaxf(rm, __shfl_xor(rm, 2, 16));
      rm = fmaxf(rm, __shfl_xor(rm, 4, 16));
      rm = fmaxf(rm, __shfl_xor(rm, 8, 16));
      float mn = fmaxf(m_st[r], rm);
      float al = __expf(m_st[r] - mn);
      m_st[r] = mn;
      float ps = 0.f;
#pragma unroll
      for (int nt = 0; nt < 4; ++nt) {
        float pv = __expf(s[nt][r] - mn);
        s[nt][r] = pv;
        ps += pv;
      }
      ps += __shfl_xor(ps, 1, 16);
      ps += __shfl_xor(ps, 2, 16);
      ps += __shfl_xor(ps, 4, 16);
      ps += __shfl_xor(ps, 8, 16);
      l_st[r] = l_st[r] * al + ps;
      alpha[r] = al;
    }
    // rescale O accumulator
#pragma unroll
    for (int nt = 0; nt < 8; ++nt)
#pragma unroll
      for (int r = 0; r < 4; ++r) o_acc[nt][r] *= alpha[r];
    // P: C-layout -> LDS -> A-layout (bf16)
#pragma unroll
    for (int nt = 0; nt < 4; ++nt)
#pragma unroll
      for (int r = 0; r < 4; ++r)
        pw[(quad * 4 + r) * 72 + nt * 16 + l15] = f2bf(s[nt][r]);
    __syncthreads();
    // O += P @ V
#pragma unroll
    for (int c2 = 0; c2 < 2; ++c2) {
      bf16x8 pf = ld_bf8(pw + l15 * 72 + c2 * 32 + quad * 8);
#pragma unroll
      for (int nt = 0; nt < 8; ++nt) {
        bf16x8 vf = ld_bf8(vb + (size_t)(nt * 16 + l15) * TSEQ + kt * 64 + c2 * 32 + quad * 8);
        o_acc[nt] = __builtin_amdgcn_mfma_f32_16x16x32_bf16(pf, vf, o_acc[nt], 0, 0, 0);
      }
    }
  }

  // epilogue: divide by l, store fp32
  float invl[4];
#pragma unroll
  for (int r = 0; r < 4; ++r) invl[r] = 1.0f / l_st[r];
#pragma unroll
  for (int nt = 0; nt < 8; ++nt)
#pragma unroll
    for (int r = 0; r < 4; ++r) {
      size_t row = (size_t)(b * TSEQ + qt * 64 + w * 16 + quad * 4 + r);
      out[row * DH + nt * 16 + l15] = o_acc[nt][r] * invl[r];
    }
}

extern "C" void kernel_launch(void* const* d_in, const int* in_sizes, int n_in,
                              void* d_out, int out_size, void* d_ws, size_t ws_size,
                              hipStream_t stream) {
  const float* x     = (const float*)d_in[0];
  const float* key   = (const float*)d_in[1];
  const float* value = (const float*)d_in[2];
  const float* w_q   = (const float*)d_in[3];
  float* out = (float*)d_out;

  // workspace layout (needs ~12.5 MB):
  char* ws = (char*)d_ws;
  unsigned short* wbf  = (unsigned short*)(ws);                         // 512 KB
  unsigned short* qrot = (unsigned short*)(ws + 524288);                // 4 MB
  unsigned short* krot = (unsigned short*)(ws + 524288 + 4194304);      // 4 MB
  unsigned short* vt   = (unsigned short*)(ws + 524288 + 2 * 4194304);  // 4 MB

  k_wconv<<<256, 256, 0, stream>>>(w_q, wbf);
  k_ropek<<<4096, 256, 0, stream>>>(key, krot);
  k_vt<<<NBATCH * (TSEQ / 64), 256, 0, stream>>>(value, vt);
  k_qproj<<<(NBATCH * TSEQ) / 64, 256, 0, stream>>>(x, wbf, qrot);
  k_attn<<<NBATCH * (TSEQ / 64), 256, 0, stream>>>(qrot, krot, vt, out);
}

// Round 2
// 451.640 us; speedup vs baseline: 1.4458x; 1.4458x over previous
//
#include <hip/hip_runtime.h>

#define TSEQ  4096
#define NBATCH 4
#define CDIM  2048
#define DH    128

typedef __bf16 bf16x8 __attribute__((ext_vector_type(8)));
typedef float  f32x4  __attribute__((ext_vector_type(4)));
typedef unsigned short u16x8 __attribute__((ext_vector_type(8)));

__device__ __forceinline__ unsigned short f2bf(float f) {
  union { float f; unsigned u; } v; v.f = f;
  unsigned r = (v.u + 0x7FFFu + ((v.u >> 16) & 1u)) >> 16;
  return (unsigned short)r;
}

__device__ __forceinline__ bf16x8 ld_bf8(const unsigned short* p) {
  return __builtin_bit_cast(bf16x8, *(const u16x8*)p);
}

// ---------------- prep: cos/sin tables [t][p], p in 0..63 ----------------
__global__ void k_trig(float* __restrict__ ct, float* __restrict__ st) {
  int i = blockIdx.x * 256 + threadIdx.x;    // TSEQ*64 entries
  int p = i & 63;
  int t = i >> 6;
  float inv = powf(10000.0f, -(float)p / 64.0f);
  float ang = (float)t * inv;
  float s, c; sincosf(ang, &s, &c);
  ct[i] = c; st[i] = s;
}

// ---------------- prep: w_q fp32 -> bf16 ----------------
__global__ void k_wconv(const float* __restrict__ w, unsigned short* __restrict__ wbf) {
  int i = blockIdx.x * 256 + threadIdx.x;
  const float4 v = *(const float4*)(w + (size_t)i * 4);
  unsigned lo = (unsigned)f2bf(v.x) | ((unsigned)f2bf(v.y) << 16);
  unsigned hi = (unsigned)f2bf(v.z) | ((unsigned)f2bf(v.w) << 16);
  uint2 o; o.x = lo; o.y = hi;
  *(uint2*)(wbf + (size_t)i * 4) = o;
}

// ---------------- prep: rope(key) -> bf16 k_rot (table-driven) ----------------
__global__ void k_ropek(const float* __restrict__ key, const float* __restrict__ ct,
                        const float* __restrict__ st, unsigned short* __restrict__ krot) {
  int g = blockIdx.x * 256 + threadIdx.x;    // pair index, NBATCH*TSEQ*64 total
  int p = g & 63;
  int row = g >> 6;                          // b*TSEQ + t
  int t = row & (TSEQ - 1);
  const float2 kv = *(const float2*)(key + (size_t)row * DH + 2 * p);
  float c = ct[t * 64 + p];
  float s = st[t * 64 + p];
  float o1 = kv.x * c - kv.y * s;
  float o2 = kv.x * s + kv.y * c;
  unsigned pk = (unsigned)f2bf(o1) | ((unsigned)f2bf(o2) << 16);
  *(unsigned*)(krot + (size_t)row * DH + 2 * p) = pk;
}

// ---------------- prep: transpose value -> bf16 v_t[b][d][t] ----------------
__global__ void k_vt(const float* __restrict__ v, unsigned short* __restrict__ vt) {
  __shared__ unsigned short S[128 * 66];
  int bid = blockIdx.x;
  int b = bid >> 6;
  int t0 = (bid & 63) * 64;
  int tid = threadIdx.x;
  int d = (tid & 31) * 4;
  int tl0 = tid >> 5;
#pragma unroll
  for (int i = 0; i < 8; ++i) {
    int tl = tl0 + i * 8;
    const float4 val = *(const float4*)(v + ((size_t)(b * TSEQ + t0 + tl)) * DH + d);
    S[(d + 0) * 66 + tl] = f2bf(val.x);
    S[(d + 1) * 66 + tl] = f2bf(val.y);
    S[(d + 2) * 66 + tl] = f2bf(val.z);
    S[(d + 3) * 66 + tl] = f2bf(val.w);
  }
  __syncthreads();
#pragma unroll
  for (int i = 0; i < 16; ++i) {
    int idx = tid + i * 256;
    int dd = idx >> 5;
    int tw = (idx & 31) * 2;
    unsigned lo = S[dd * 66 + tw];
    unsigned hi = S[dd * 66 + tw + 1];
    *(unsigned*)(vt + ((size_t)(b * DH + dd)) * TSEQ + t0 + tw) = lo | (hi << 16);
  }
}

// ------- q projection GEMM: 16-row tile/block, K split over 4 waves, fused RoPE -------
__global__ __launch_bounds__(256) void k_qproj(const float* __restrict__ x,
                                               const unsigned short* __restrict__ wbf,
                                               const float* __restrict__ ct,
                                               const float* __restrict__ st,
                                               unsigned short* __restrict__ qrot) {
  __shared__ float Of[16 * 128];
  int bid = blockIdx.x;                  // 1024 blocks, 16 rows each
  int tid = threadIdx.x;
  int w = tid >> 6;
  int lane = tid & 63;
  int l15 = lane & 15;
  int quad = lane >> 4;
  int m0 = bid * 16;

  const float* xrow = x + (size_t)(m0 + l15) * CDIM;

  f32x4 acc[8];
#pragma unroll
  for (int i = 0; i < 8; ++i) acc[i] = (f32x4){0.f, 0.f, 0.f, 0.f};

  int kbase = w * (CDIM / 4);            // 512 per wave
  for (int it = 0; it < CDIM / 128; ++it) {   // 16 iterations
    int k0 = kbase + it * 32 + quad * 8;
    float4 a0 = *(const float4*)(xrow + k0);
    float4 a1 = *(const float4*)(xrow + k0 + 4);
    u16x8 au;
    au[0] = f2bf(a0.x); au[1] = f2bf(a0.y); au[2] = f2bf(a0.z); au[3] = f2bf(a0.w);
    au[4] = f2bf(a1.x); au[5] = f2bf(a1.y); au[6] = f2bf(a1.z); au[7] = f2bf(a1.w);
    bf16x8 af = __builtin_bit_cast(bf16x8, au);
#pragma unroll
    for (int nt = 0; nt < 8; ++nt) {
      bf16x8 bf = ld_bf8(wbf + (size_t)(nt * 16 + l15) * CDIM + k0);
      acc[nt] = __builtin_amdgcn_mfma_f32_16x16x32_bf16(af, bf, acc[nt], 0, 0, 0);
    }
  }

  // staged merge of the 4 partial accumulators into LDS
  for (int s = 0; s < 4; ++s) {
    if (w == s) {
#pragma unroll
      for (int nt = 0; nt < 8; ++nt)
#pragma unroll
        for (int r = 0; r < 4; ++r) {
          int row = quad * 4 + r, col = nt * 16 + l15;
          if (s == 0) Of[row * 128 + col] = acc[nt][r];
          else        Of[row * 128 + col] += acc[nt][r];
        }
    }
    __syncthreads();
  }

  // cooperative RoPE + scale epilogue (table-driven)
  const float scale = 0.08838834764831845f;  // 128^-0.5
#pragma unroll
  for (int k = 0; k < 4; ++k) {
    int pi = tid + k * 256;                // 1024 pairs = 16 rows x 64 pairs
    int row = pi >> 6;
    int p = pi & 63;
    int t = (m0 + row) & (TSEQ - 1);
    float x1 = Of[row * 128 + 2 * p];
    float x2 = Of[row * 128 + 2 * p + 1];
    float c = ct[t * 64 + p];
    float s = st[t * 64 + p];
    float o1 = (x1 * c - x2 * s) * scale;
    float o2 = (x1 * s + x2 * c) * scale;
    unsigned pk = (unsigned)f2bf(o1) | ((unsigned)f2bf(o2) << 16);
    *(unsigned*)(qrot + (size_t)(m0 + row) * DH + 2 * p) = pk;
  }
}

// ------- causal flash attention: 16-row q-tile/block, K-tiles split over 4 waves -------
__global__ __launch_bounds__(256) void k_attn(const unsigned short* __restrict__ qrot,
                                              const unsigned short* __restrict__ krot,
                                              const unsigned short* __restrict__ vt,
                                              float* __restrict__ out) {
  __shared__ unsigned short Pl[4 * 16 * 72];   // per-wave P tiles
  __shared__ float Of[16 * 128];
  __shared__ float Mw[4][16];
  __shared__ float Lw[4][16];
  __shared__ float Lfin[16];

  int bid = blockIdx.x;                  // B * T/16 = 1024
  int b = bid >> 8;
  int q16 = bid & 255;
  int tid = threadIdx.x;
  int w = tid >> 6;
  int lane = tid & 63;
  int l15 = lane & 15;
  int quad = lane >> 4;
  unsigned short* pw = Pl + w * 16 * 72;

  int m0 = q16 * 16;                     // first q row (within batch)
  int nkt = (q16 >> 2) + 1;              // number of 64-key tiles

  bf16x8 qf[4];
  {
    const unsigned short* qb = qrot + ((size_t)(b * TSEQ + m0 + l15)) * DH + quad * 8;
#pragma unroll
    for (int c = 0; c < 4; ++c) qf[c] = ld_bf8(qb + c * 32);
  }

  f32x4 o_acc[8];
#pragma unroll
  for (int i = 0; i < 8; ++i) o_acc[i] = (f32x4){0.f, 0.f, 0.f, 0.f};
  float m_st[4], l_st[4];
#pragma unroll
  for (int r = 0; r < 4; ++r) { m_st[r] = -INFINITY; l_st[r] = 0.f; }

  const unsigned short* kb = krot + (size_t)b * TSEQ * DH;
  const unsigned short* vb = vt + (size_t)b * DH * TSEQ;

  for (int kt = w; kt < nkt; kt += 4) {
    // S = Q @ K^T  (16 q-rows x 64 keys)
    f32x4 s[4];
#pragma unroll
    for (int nt = 0; nt < 4; ++nt) {
      s[nt] = (f32x4){0.f, 0.f, 0.f, 0.f};
      const unsigned short* kr = kb + (size_t)(kt * 64 + nt * 16 + l15) * DH + quad * 8;
#pragma unroll
      for (int c = 0; c < 4; ++c) {
        bf16x8 bf = ld_bf8(kr + c * 32);
        s[nt] = __builtin_amdgcn_mfma_f32_16x16x32_bf16(qf[c], bf, s[nt], 0, 0, 0);
      }
    }
    // causal mask: only the last (diagonal) tile is partial
    if (kt == nkt - 1) {
#pragma unroll
      for (int nt = 0; nt < 4; ++nt)
#pragma unroll
        for (int r = 0; r < 4; ++r) {
          int key_g = kt * 64 + nt * 16 + l15;
          int q_g = m0 + quad * 4 + r;
          if (key_g > q_g) s[nt][r] = -INFINITY;
        }
    }
    // online softmax (per quad: row r in 16 lanes)
    float alpha[4];
#pragma unroll
    for (int r = 0; r < 4; ++r) {
      float rm = fmaxf(fmaxf(s[0][r], s[1][r]), fmaxf(s[2][r], s[3][r]));
      rm = fmaxf(rm, __shfl_xor(rm, 1, 16));
      rm = fmaxf(rm, __shfl_xor(rm, 2, 16));
      rm = fmaxf(rm, __shfl_xor(rm, 4, 16));
      rm = fmaxf(rm, __shfl_xor(rm, 8, 16));
      float mn = fmaxf(m_st[r], rm);
      float al = __expf(m_st[r] - mn);
      m_st[r] = mn;
      float ps = 0.f;
#pragma unroll
      for (int nt = 0; nt < 4; ++nt) {
        float pv = __expf(s[nt][r] - mn);
        s[nt][r] = pv;
        ps += pv;
      }
      ps += __shfl_xor(ps, 1, 16);
      ps += __shfl_xor(ps, 2, 16);
      ps += __shfl_xor(ps, 4, 16);
      ps += __shfl_xor(ps, 8, 16);
      l_st[r] = l_st[r] * al + ps;
      alpha[r] = al;
    }
#pragma unroll
    for (int nt = 0; nt < 8; ++nt)
#pragma unroll
      for (int r = 0; r < 4; ++r) o_acc[nt][r] *= alpha[r];
    // P: C-layout -> per-wave LDS -> A-layout (wave-synchronous, no barrier)
#pragma unroll
    for (int nt = 0; nt < 4; ++nt)
#pragma unroll
      for (int r = 0; r < 4; ++r)
        pw[(quad * 4 + r) * 72 + nt * 16 + l15] = f2bf(s[nt][r]);
#pragma unroll
    for (int c2 = 0; c2 < 2; ++c2) {
      bf16x8 pf = ld_bf8(pw + l15 * 72 + c2 * 32 + quad * 8);
#pragma unroll
      for (int nt = 0; nt < 8; ++nt) {
        bf16x8 vf = ld_bf8(vb + (size_t)(nt * 16 + l15) * TSEQ + kt * 64 + c2 * 32 + quad * 8);
        o_acc[nt] = __builtin_amdgcn_mfma_f32_16x16x32_bf16(pf, vf, o_acc[nt], 0, 0, 0);
      }
    }
  }

  // ---- block-level split-K merge ----
  if (l15 == 0) {
#pragma unroll
    for (int r = 0; r < 4; ++r) {
      Mw[w][quad * 4 + r] = m_st[r];
      Lw[w][quad * 4 + r] = l_st[r];
    }
  }
  __syncthreads();

  float f[4];
#pragma unroll
  for (int r = 0; r < 4; ++r) {
    int row = quad * 4 + r;
    float M = fmaxf(fmaxf(Mw[0][row], Mw[1][row]), fmaxf(Mw[2][row], Mw[3][row]));
    f[r] = __expf(m_st[r] - M);
  }
  if (tid < 16) {
    float M = fmaxf(fmaxf(Mw[0][tid], Mw[1][tid]), fmaxf(Mw[2][tid], Mw[3][tid]));
    float L = 0.f;
#pragma unroll
    for (int ww = 0; ww < 4; ++ww) L += __expf(Mw[ww][tid] - M) * Lw[ww][tid];
    Lfin[tid] = L;
  }

  for (int s = 0; s < 4; ++s) {
    if (w == s) {
#pragma unroll
      for (int nt = 0; nt < 8; ++nt)
#pragma unroll
        for (int r = 0; r < 4; ++r) {
          int row = quad * 4 + r, col = nt * 16 + l15;
          float v = f[r] * o_acc[nt][r];
          if (s == 0) Of[row * 128 + col] = v;
          else        Of[row * 128 + col] += v;
        }
    }
    __syncthreads();
  }

  // write out (fp32), coalesced
#pragma unroll
  for (int k = 0; k < 8; ++k) {
    int idx = tid + k * 256;               // 2048 elements
    int row = idx >> 7, col = idx & 127;
    out[((size_t)(b * TSEQ + m0 + row)) * DH + col] = Of[row * 128 + col] / Lfin[row];
  }
}

extern "C" void kernel_launch(void* const* d_in, const int* in_sizes, int n_in,
                              void* d_out, int out_size, void* d_ws, size_t ws_size,
                              hipStream_t stream) {
  const float* x     = (const float*)d_in[0];
  const float* key   = (const float*)d_in[1];
  const float* value = (const float*)d_in[2];
  const float* w_q   = (const float*)d_in[3];
  float* out = (float*)d_out;

  // workspace layout (~14.5 MB)
  char* ws = (char*)d_ws;
  unsigned short* wbf  = (unsigned short*)(ws);                          // 512 KB
  unsigned short* qrot = (unsigned short*)(ws + (512u << 10));           // 4 MB
  unsigned short* krot = (unsigned short*)(ws + (512u << 10) + (4u << 20));
  unsigned short* vt   = (unsigned short*)(ws + (512u << 10) + (8u << 20));
  float* ct            = (float*)(ws + (512u << 10) + (12u << 20));      // 1 MB
  float* st            = (float*)(ws + (512u << 10) + (13u << 20));      // 1 MB

  k_trig<<<(TSEQ * 64) / 256, 256, 0, stream>>>(ct, st);
  k_wconv<<<256, 256, 0, stream>>>(w_q, wbf);
  k_ropek<<<(NBATCH * TSEQ * 64) / 256, 256, 0, stream>>>(key, ct, st, krot);
  k_vt<<<NBATCH * (TSEQ / 64), 256, 0, stream>>>(value, vt);
  k_qproj<<<(NBATCH * TSEQ) / 16, 256, 0, stream>>>(x, wbf, ct, st, qrot);
  k_attn<<<NBATCH * (TSEQ / 16), 256, 0, stream>>>(qrot, krot, vt, out);
}

// Round 3
// 374.355 us; speedup vs baseline: 1.7443x; 1.2064x over previous
//
#include <hip/hip_runtime.h>

#define TSEQ  4096
#define NBATCH 4
#define CDIM  2048
#define DH    128

typedef __bf16 bf16x8 __attribute__((ext_vector_type(8)));
typedef float  f32x4  __attribute__((ext_vector_type(4)));
typedef unsigned short u16x8 __attribute__((ext_vector_type(8)));
typedef unsigned short u16;

__device__ __forceinline__ u16 f2bf(float f) {
  union { float f; unsigned u; } v; v.f = f;
  unsigned r = (v.u + 0x7FFFu + ((v.u >> 16) & 1u)) >> 16;
  return (u16)r;
}

__device__ __forceinline__ float bf2f(u16 h) {
  union { unsigned u; float f; } v; v.u = ((unsigned)h) << 16;
  return v.f;
}

__device__ __forceinline__ bf16x8 ld_bf8(const u16* p) {
  return __builtin_bit_cast(bf16x8, *(const u16x8*)p);
}

// DPP cross-lane (VALU pipe, not DS pipe): reduce over each 16-lane row
template<int CTRL>
__device__ __forceinline__ float dppmv(float x) {
  return __builtin_bit_cast(float,
    __builtin_amdgcn_update_dpp(0, __builtin_bit_cast(int, x), CTRL, 0xF, 0xF, true));
}
__device__ __forceinline__ float red_max16(float v) {
  v = fmaxf(v, dppmv<0xB1>(v));   // quad_perm xor1
  v = fmaxf(v, dppmv<0x4E>(v));   // quad_perm xor2
  v = fmaxf(v, dppmv<0x124>(v));  // row_ror:4
  v = fmaxf(v, dppmv<0x128>(v));  // row_ror:8
  return v;
}
__device__ __forceinline__ float red_sum16(float v) {
  v += dppmv<0xB1>(v);
  v += dppmv<0x4E>(v);
  v += dppmv<0x124>(v);
  v += dppmv<0x128>(v);
  return v;
}

// ---------------- prep: cos/sin tables [t][p], p in 0..63 ----------------
__global__ void k_trig(float* __restrict__ ct, float* __restrict__ st) {
  int i = blockIdx.x * 256 + threadIdx.x;    // TSEQ*64 entries
  int p = i & 63;
  int t = i >> 6;
  float inv = powf(10000.0f, -(float)p / 64.0f);
  float ang = (float)t * inv;
  float s, c; sincosf(ang, &s, &c);
  ct[i] = c; st[i] = s;
}

// ---------------- prep: w_q fp32 -> bf16 ----------------
__global__ void k_wconv(const float* __restrict__ w, u16* __restrict__ wbf) {
  int i = blockIdx.x * 256 + threadIdx.x;
  const float4 v = *(const float4*)(w + (size_t)i * 4);
  unsigned lo = (unsigned)f2bf(v.x) | ((unsigned)f2bf(v.y) << 16);
  unsigned hi = (unsigned)f2bf(v.z) | ((unsigned)f2bf(v.w) << 16);
  uint2 o; o.x = lo; o.y = hi;
  *(uint2*)(wbf + (size_t)i * 4) = o;
}

// ---------------- prep: rope(key) -> bf16 k_rot (table-driven) ----------------
__global__ void k_ropek(const float* __restrict__ key, const float* __restrict__ ct,
                        const float* __restrict__ st, u16* __restrict__ krot) {
  int g = blockIdx.x * 256 + threadIdx.x;    // pair index, NBATCH*TSEQ*64 total
  int p = g & 63;
  int row = g >> 6;                          // b*TSEQ + t
  int t = row & (TSEQ - 1);
  const float2 kv = *(const float2*)(key + (size_t)row * DH + 2 * p);
  float c = ct[t * 64 + p];
  float s = st[t * 64 + p];
  float o1 = kv.x * c - kv.y * s;
  float o2 = kv.x * s + kv.y * c;
  unsigned pk = (unsigned)f2bf(o1) | ((unsigned)f2bf(o2) << 16);
  *(unsigned*)(krot + (size_t)row * DH + 2 * p) = pk;
}

// ---------------- prep: transpose value -> bf16 v_t[b][d][t] ----------------
__global__ void k_vt(const float* __restrict__ v, u16* __restrict__ vt) {
  __shared__ u16 S[128 * 66];
  int bid = blockIdx.x;
  int b = bid >> 6;
  int t0 = (bid & 63) * 64;
  int tid = threadIdx.x;
  int d = (tid & 31) * 4;
  int tl0 = tid >> 5;
#pragma unroll
  for (int i = 0; i < 8; ++i) {
    int tl = tl0 + i * 8;
    const float4 val = *(const float4*)(v + ((size_t)(b * TSEQ + t0 + tl)) * DH + d);
    S[(d + 0) * 66 + tl] = f2bf(val.x);
    S[(d + 1) * 66 + tl] = f2bf(val.y);
    S[(d + 2) * 66 + tl] = f2bf(val.z);
    S[(d + 3) * 66 + tl] = f2bf(val.w);
  }
  __syncthreads();
#pragma unroll
  for (int i = 0; i < 16; ++i) {
    int idx = tid + i * 256;
    int dd = idx >> 5;
    int tw = (idx & 31) * 2;
    unsigned lo = S[dd * 66 + tw];
    unsigned hi = S[dd * 66 + tw + 1];
    *(unsigned*)(vt + ((size_t)(b * DH + dd)) * TSEQ + t0 + tw) = lo | (hi << 16);
  }
}

// ------- q projection GEMM: 16-row tile/block, K split over 4 waves, fused RoPE -------
__global__ __launch_bounds__(256) void k_qproj(const float* __restrict__ x,
                                               const u16* __restrict__ wbf,
                                               const float* __restrict__ ct,
                                               const float* __restrict__ st,
                                               u16* __restrict__ qrot) {
  __shared__ float Of[16 * 128];
  int bid = blockIdx.x;                  // 1024 blocks, 16 rows each
  int tid = threadIdx.x;
  int w = tid >> 6;
  int lane = tid & 63;
  int l15 = lane & 15;
  int quad = lane >> 4;
  int m0 = bid * 16;

  const float* xrow = x + (size_t)(m0 + l15) * CDIM;

  f32x4 acc[8];
#pragma unroll
  for (int i = 0; i < 8; ++i) acc[i] = (f32x4){0.f, 0.f, 0.f, 0.f};

  int kbase = w * (CDIM / 4);            // 512 per wave
  for (int it = 0; it < CDIM / 128; ++it) {   // 16 iterations
    int k0 = kbase + it * 32 + quad * 8;
    float4 a0 = *(const float4*)(xrow + k0);
    float4 a1 = *(const float4*)(xrow + k0 + 4);
    u16x8 au;
    au[0] = f2bf(a0.x); au[1] = f2bf(a0.y); au[2] = f2bf(a0.z); au[3] = f2bf(a0.w);
    au[4] = f2bf(a1.x); au[5] = f2bf(a1.y); au[6] = f2bf(a1.z); au[7] = f2bf(a1.w);
    bf16x8 af = __builtin_bit_cast(bf16x8, au);
#pragma unroll
    for (int nt = 0; nt < 8; ++nt) {
      bf16x8 bf = ld_bf8(wbf + (size_t)(nt * 16 + l15) * CDIM + k0);
      acc[nt] = __builtin_amdgcn_mfma_f32_16x16x32_bf16(af, bf, acc[nt], 0, 0, 0);
    }
  }

  // staged merge of the 4 partial accumulators into LDS
  for (int s = 0; s < 4; ++s) {
    if (w == s) {
#pragma unroll
      for (int nt = 0; nt < 8; ++nt)
#pragma unroll
        for (int r = 0; r < 4; ++r) {
          int row = quad * 4 + r, col = nt * 16 + l15;
          if (s == 0) Of[row * 128 + col] = acc[nt][r];
          else        Of[row * 128 + col] += acc[nt][r];
        }
    }
    __syncthreads();
  }

  // cooperative RoPE + scale epilogue (table-driven)
  const float scale = 0.08838834764831845f;  // 128^-0.5
#pragma unroll
  for (int k = 0; k < 4; ++k) {
    int pi = tid + k * 256;                // 1024 pairs = 16 rows x 64 pairs
    int row = pi >> 6;
    int p = pi & 63;
    int t = (m0 + row) & (TSEQ - 1);
    float x1 = Of[row * 128 + 2 * p];
    float x2 = Of[row * 128 + 2 * p + 1];
    float c = ct[t * 64 + p];
    float s = st[t * 64 + p];
    float o1 = (x1 * c - x2 * s) * scale;
    float o2 = (x1 * s + x2 * c) * scale;
    unsigned pk = (unsigned)f2bf(o1) | ((unsigned)f2bf(o2) << 16);
    *(unsigned*)(qrot + (size_t)(m0 + row) * DH + 2 * p) = pk;
  }
}

// ------- causal flash attention: uniform work units (b, 64-row q-tile, <=16 k-tiles) -------
// 4 waves per block each own 16 q-rows; K/V tiles LDS-staged (frag-major) and shared.
// Emits unnormalized bf16 partial O + per-row (m,l); k_merge combines.
__global__ __launch_bounds__(256) void k_attn(const u16* __restrict__ qrot,
                                              const u16* __restrict__ krot,
                                              const u16* __restrict__ vt,
                                              u16* __restrict__ Opart,
                                              float2* __restrict__ ml) {
  __shared__ u16 Kl[16 * 64 * 8];    // [chunk16][keyrow64][8 elems]  16 KB
  __shared__ u16 Vl[8 * 128 * 8];    // [chunk8][drow128][8 elems]    16 KB
  __shared__ u16 Pl[4 * 16 * 72];    // per-wave P tiles               9 KB

  int bid = blockIdx.x;              // 640 = 4 batches * 160 units
  int b = bid / 160;
  int u = bid - b * 160;
  int qt, kc;
  if (u < 16)      { qt = u;                kc = 0; }
  else if (u < 48) { qt = 16 + ((u - 16) >> 1); kc = (u - 16) & 1; }
  else if (u < 96) { int q3 = (u - 48) / 3; qt = 32 + q3; kc = (u - 48) - 3 * q3; }
  else             { qt = 48 + ((u - 96) >> 2); kc = (u - 96) & 3; }
  int kt0 = kc * 16;
  int kt1 = min(kt0 + 16, qt + 1);

  int tid = threadIdx.x;
  int w = tid >> 6;
  int lane = tid & 63;
  int l15 = lane & 15;
  int quad = lane >> 4;
  u16* pw = Pl + w * 16 * 72;

  // staging thread assignments
  int rK  = tid & 63;   int jgK = tid >> 6;    // K: key-row, chunk-group (4 chunks each)
  int dV  = tid & 127;  int hV  = tid >> 7;    // V: d-row, chunk-half (4 chunks each)

  const u16* kb = krot + (size_t)b * TSEQ * DH;
  const u16* vb = vt + (size_t)b * DH * TSEQ;

  // Q fragments in registers
  bf16x8 qf[4];
  {
    const u16* qb = qrot + ((size_t)(b * TSEQ + qt * 64 + w * 16 + l15)) * DH + quad * 8;
#pragma unroll
    for (int c = 0; c < 4; ++c) qf[c] = ld_bf8(qb + c * 32);
  }

  f32x4 o_acc[8];
#pragma unroll
  for (int i = 0; i < 8; ++i) o_acc[i] = (f32x4){0.f, 0.f, 0.f, 0.f};
  float m_st[4], l_st[4];
#pragma unroll
  for (int r = 0; r < 4; ++r) { m_st[r] = -INFINITY; l_st[r] = 0.f; }

  // prefetch first tile into registers
  u16x8 kr[4], vr[4];
  {
    const u16* ks = kb + (size_t)(kt0 * 64 + rK) * DH + jgK * 32;
    const u16* vs = vb + (size_t)dV * TSEQ + kt0 * 64 + hV * 32;
#pragma unroll
    for (int i = 0; i < 4; ++i) { kr[i] = *(const u16x8*)(ks + i * 8); vr[i] = *(const u16x8*)(vs + i * 8); }
  }

  for (int kt = kt0; kt < kt1; ++kt) {
    __syncthreads();                 // LDS free (all waves done with previous tile)
#pragma unroll
    for (int i = 0; i < 4; ++i) {
      *(u16x8*)&Kl[((jgK * 4 + i) * 64 + rK) * 8] = kr[i];
      *(u16x8*)&Vl[((hV * 4 + i) * 128 + dV) * 8] = vr[i];
    }
    __syncthreads();                 // tile staged
    if (kt + 1 < kt1) {              // prefetch next tile (in flight during compute)
      const u16* ks = kb + (size_t)((kt + 1) * 64 + rK) * DH + jgK * 32;
      const u16* vs = vb + (size_t)dV * TSEQ + (kt + 1) * 64 + hV * 32;
#pragma unroll
      for (int i = 0; i < 4; ++i) { kr[i] = *(const u16x8*)(ks + i * 8); vr[i] = *(const u16x8*)(vs + i * 8); }
    }

    // S = Q @ K^T (16 q-rows x 64 keys per wave)
    f32x4 s[4];
#pragma unroll
    for (int nt = 0; nt < 4; ++nt) {
      s[nt] = (f32x4){0.f, 0.f, 0.f, 0.f};
#pragma unroll
      for (int c = 0; c < 4; ++c) {
        bf16x8 kf = ld_bf8(&Kl[((c * 4 + quad) * 64 + nt * 16 + l15) * 8]);
        s[nt] = __builtin_amdgcn_mfma_f32_16x16x32_bf16(qf[c], kf, s[nt], 0, 0, 0);
      }
    }
    // causal mask on the diagonal tile
    if (kt == qt) {
#pragma unroll
      for (int nt = 0; nt < 4; ++nt)
#pragma unroll
        for (int r = 0; r < 4; ++r) {
          if (nt * 16 + l15 > w * 16 + quad * 4 + r) s[nt][r] = -INFINITY;
        }
    }
    // online softmax per row (DPP reductions, VALU pipe)
    float alpha[4];
#pragma unroll
    for (int r = 0; r < 4; ++r) {
      float rm = fmaxf(fmaxf(s[0][r], s[1][r]), fmaxf(s[2][r], s[3][r]));
      rm = red_max16(rm);
      float mn = fmaxf(m_st[r], rm);
      float al = __expf(m_st[r] - mn);
      m_st[r] = mn;
      float ps = 0.f;
#pragma unroll
      for (int nt = 0; nt < 4; ++nt) {
        float pv = __expf(s[nt][r] - mn);
        s[nt][r] = pv;
        ps += pv;
      }
      ps = red_sum16(ps);
      l_st[r] = l_st[r] * al + ps;
      alpha[r] = al;
    }
#pragma unroll
    for (int nt = 0; nt < 8; ++nt)
#pragma unroll
      for (int r = 0; r < 4; ++r) o_acc[nt][r] *= alpha[r];
    // P: C-layout -> per-wave LDS -> A-layout (wave-synchronous)
#pragma unroll
    for (int nt = 0; nt < 4; ++nt)
#pragma unroll
      for (int r = 0; r < 4; ++r)
        pw[(quad * 4 + r) * 72 + nt * 16 + l15] = f2bf(s[nt][r]);
    // O += P @ V
#pragma unroll
    for (int c2 = 0; c2 < 2; ++c2) {
      bf16x8 pf = ld_bf8(pw + l15 * 72 + c2 * 32 + quad * 8);
#pragma unroll
      for (int nt = 0; nt < 8; ++nt) {
        bf16x8 vf = ld_bf8(&Vl[((c2 * 4 + quad) * 128 + nt * 16 + l15) * 8]);
        o_acc[nt] = __builtin_amdgcn_mfma_f32_16x16x32_bf16(pf, vf, o_acc[nt], 0, 0, 0);
      }
    }
  }

  // epilogue: write unnormalized bf16 partial + (m,l)
  int slot = bid;
  u16* op = Opart + (size_t)slot * 8192;
#pragma unroll
  for (int nt = 0; nt < 8; ++nt)
#pragma unroll
    for (int r = 0; r < 4; ++r)
      op[(w * 16 + quad * 4 + r) * 128 + nt * 16 + l15] = f2bf(o_acc[nt][r]);
  if (l15 == 0) {
#pragma unroll
    for (int r = 0; r < 4; ++r) {
      float2 p; p.x = m_st[r]; p.y = l_st[r];
      ml[slot * 64 + w * 16 + quad * 4 + r] = p;
    }
  }
}

// ------- merge partials: one block per (b, 64-row q-tile) -------
__global__ __launch_bounds__(256) void k_merge(const u16* __restrict__ Opart,
                                               const float2* __restrict__ ml,
                                               float* __restrict__ out) {
  __shared__ float wgt[4][64];
  __shared__ float invL[64];
  int bid = blockIdx.x;              // b*64 + qt
  int b = bid >> 6, qt = bid & 63;
  int C = 1 + (qt >> 4);
  int base = b * 160 + (qt < 16 ? qt
                       : qt < 32 ? 16 + 2 * (qt - 16)
                       : qt < 48 ? 48 + 3 * (qt - 32)
                       : 96 + 4 * (qt - 48));
  int tid = threadIdx.x;
  if (tid < 64) {
    float mv[4], lv[4];
    float M = -INFINITY;
    for (int uu = 0; uu < C; ++uu) {
      float2 p = ml[(base + uu) * 64 + tid];
      mv[uu] = p.x; lv[uu] = p.y;
      M = fmaxf(M, p.x);
    }
    float L = 0.f;
    for (int uu = 0; uu < C; ++uu) {
      float wv = __expf(mv[uu] - M);
      wgt[uu][tid] = wv;
      L += wv * lv[uu];
    }
    invL[tid] = 1.f / L;
  }
  __syncthreads();
#pragma unroll
  for (int k = 0; k < 32; ++k) {
    int e = tid + k * 256;           // 8192 = 64 rows x 128 cols
    int row = e >> 7;
    float acc = 0.f;
    for (int uu = 0; uu < C; ++uu)
      acc += wgt[uu][row] * bf2f(Opart[(size_t)(base + uu) * 8192 + e]);
    out[(size_t)(b * TSEQ + qt * 64) * DH + e] = acc * invL[row];
  }
}

extern "C" void kernel_launch(void* const* d_in, const int* in_sizes, int n_in,
                              void* d_out, int out_size, void* d_ws, size_t ws_size,
                              hipStream_t stream) {
  const float* x     = (const float*)d_in[0];
  const float* key   = (const float*)d_in[1];
  const float* value = (const float*)d_in[2];
  const float* w_q   = (const float*)d_in[3];
  float* out = (float*)d_out;

  // workspace layout (~25 MB)
  char* ws = (char*)d_ws;
  u16* wbf    = (u16*)(ws);                                  // 512 KB
  u16* qrot   = (u16*)(ws + (512u << 10));                   // 4 MB
  u16* krot   = (u16*)(ws + (512u << 10) + (4u << 20));      // 4 MB
  u16* vt     = (u16*)(ws + (512u << 10) + (8u << 20));      // 4 MB
  float* ct   = (float*)(ws + (512u << 10) + (12u << 20));   // 1 MB
  float* st   = (float*)(ws + (512u << 10) + (13u << 20));   // 1 MB
  u16* Opart  = (u16*)(ws + (512u << 10) + (14u << 20));     // 640*8192*2 = 10 MB
  float2* ml  = (float2*)(ws + (512u << 10) + (24u << 20));  // 640*64*8 = 320 KB

  k_trig<<<(TSEQ * 64) / 256, 256, 0, stream>>>(ct, st);
  k_wconv<<<256, 256, 0, stream>>>(w_q, wbf);
  k_ropek<<<(NBATCH * TSEQ * 64) / 256, 256, 0, stream>>>(key, ct, st, krot);
  k_vt<<<NBATCH * (TSEQ / 64), 256, 0, stream>>>(value, vt);
  k_qproj<<<(NBATCH * TSEQ) / 16, 256, 0, stream>>>(x, wbf, ct, st, qrot);
  k_attn<<<NBATCH * 160, 256, 0, stream>>>(qrot, krot, vt, Opart, ml);
  k_merge<<<NBATCH * 64, 256, 0, stream>>>(Opart, ml, out);
}

// Round 5
// 340.016 us; speedup vs baseline: 1.9205x; 1.1010x over previous
//
#include <hip/hip_runtime.h>
#include <hip/hip_bf16.h>

#define TSEQ  4096
#define NBATCH 4
#define CDIM  2048
#define DH    128

typedef __bf16 bf16x8 __attribute__((ext_vector_type(8)));
typedef float  f32x4  __attribute__((ext_vector_type(4)));
typedef unsigned short u16x8 __attribute__((ext_vector_type(8)));
typedef unsigned       u32x4 __attribute__((ext_vector_type(4)));
typedef unsigned short u16;

__device__ __forceinline__ u16 f2bf(float f) {
  union { float f; unsigned u; } v; v.f = f;
  unsigned r = (v.u + 0x7FFFu + ((v.u >> 16) & 1u)) >> 16;
  return (u16)r;
}

__device__ __forceinline__ float bf2f(u16 h) {
  union { unsigned u; float f; } v; v.u = ((unsigned)h) << 16;
  return v.f;
}

__device__ __forceinline__ bf16x8 ld_bf8(const u16* p) {
  return __builtin_bit_cast(bf16x8, *(const u16x8*)p);
}

// packed fp32->bf16 (v_cvt_pk_bf16_f32)
__device__ __forceinline__ unsigned pk2(float lo, float hi) {
  float2 f; f.x = lo; f.y = hi;
  __hip_bfloat162 h = __float22bfloat162_rn(f);
  unsigned r;
  __builtin_memcpy(&r, &h, 4);
  return r;
}
__device__ __forceinline__ bf16x8 cvt8(float4 a, float4 b) {
  u32x4 u;
  u[0] = pk2(a.x, a.y); u[1] = pk2(a.z, a.w);
  u[2] = pk2(b.x, b.y); u[3] = pk2(b.z, b.w);
  return __builtin_bit_cast(bf16x8, u);
}

// DPP cross-lane (VALU pipe): reduce over each 16-lane row
template<int CTRL>
__device__ __forceinline__ float dppmv(float x) {
  return __builtin_bit_cast(float,
    __builtin_amdgcn_update_dpp(0, __builtin_bit_cast(int, x), CTRL, 0xF, 0xF, true));
}
__device__ __forceinline__ float red_max16(float v) {
  v = fmaxf(v, dppmv<0xB1>(v));
  v = fmaxf(v, dppmv<0x4E>(v));
  v = fmaxf(v, dppmv<0x124>(v));
  v = fmaxf(v, dppmv<0x128>(v));
  return v;
}
__device__ __forceinline__ float red_sum16(float v) {
  v += dppmv<0xB1>(v);
  v += dppmv<0x4E>(v);
  v += dppmv<0x124>(v);
  v += dppmv<0x128>(v);
  return v;
}

// ---------------- prep: cos/sin tables [t][p], p in 0..63 ----------------
__global__ void k_trig(float* __restrict__ ct, float* __restrict__ st) {
  int i = blockIdx.x * 256 + threadIdx.x;
  int p = i & 63;
  int t = i >> 6;
  float inv = powf(10000.0f, -(float)p / 64.0f);
  float ang = (float)t * inv;
  float s, c; sincosf(ang, &s, &c);
  ct[i] = c; st[i] = s;
}

// ---------------- prep: w_q fp32 -> bf16 ----------------
__global__ void k_wconv(const float* __restrict__ w, u16* __restrict__ wbf) {
  int i = blockIdx.x * 256 + threadIdx.x;
  const float4 v = *(const float4*)(w + (size_t)i * 4);
  uint2 o; o.x = pk2(v.x, v.y); o.y = pk2(v.z, v.w);
  *(uint2*)(wbf + (size_t)i * 4) = o;
}

// ---------------- prep: rope(key) -> bf16 k_rot (table-driven) ----------------
__global__ void k_ropek(const float* __restrict__ key, const float* __restrict__ ct,
                        const float* __restrict__ st, u16* __restrict__ krot) {
  int g = blockIdx.x * 256 + threadIdx.x;
  int p = g & 63;
  int row = g >> 6;
  int t = row & (TSEQ - 1);
  const float2 kv = *(const float2*)(key + (size_t)row * DH + 2 * p);
  float c = ct[t * 64 + p];
  float s = st[t * 64 + p];
  float o1 = kv.x * c - kv.y * s;
  float o2 = kv.x * s + kv.y * c;
  *(unsigned*)(krot + (size_t)row * DH + 2 * p) = pk2(o1, o2);
}

// ---------------- prep: transpose value -> bf16 v_t[b][d][t] ----------------
__global__ void k_vt(const float* __restrict__ v, u16* __restrict__ vt) {
  __shared__ u16 S[128 * 66];
  int bid = blockIdx.x;
  int b = bid >> 6;
  int t0 = (bid & 63) * 64;
  int tid = threadIdx.x;
  int d = (tid & 31) * 4;
  int tl0 = tid >> 5;
#pragma unroll
  for (int i = 0; i < 8; ++i) {
    int tl = tl0 + i * 8;
    const float4 val = *(const float4*)(v + ((size_t)(b * TSEQ + t0 + tl)) * DH + d);
    S[(d + 0) * 66 + tl] = f2bf(val.x);
    S[(d + 1) * 66 + tl] = f2bf(val.y);
    S[(d + 2) * 66 + tl] = f2bf(val.z);
    S[(d + 3) * 66 + tl] = f2bf(val.w);
  }
  __syncthreads();
#pragma unroll
  for (int i = 0; i < 16; ++i) {
    int idx = tid + i * 256;
    int dd = idx >> 5;
    int tw = (idx & 31) * 2;
    unsigned lo = S[dd * 66 + tw];
    unsigned hi = S[dd * 66 + tw + 1];
    *(unsigned*)(vt + ((size_t)(b * DH + dd)) * TSEQ + t0 + tw) = lo | (hi << 16);
  }
}

// ------- q projection: LDS-staged GEMM, 32-row tiles, full-K per block, fused RoPE -------
// 512 blocks (2/CU). A-tile (32x64 fp32, stride 68 pad) staged coalesced; waves own
// 2 m-tiles x 2 n-tiles; B-frags from L2-resident wbf; RoPE epilogue via shfl_xor.
__global__ __launch_bounds__(256, 2) void k_qproj(const float* __restrict__ x,
                                                  const u16* __restrict__ wbf,
                                                  const float* __restrict__ ct,
                                                  const float* __restrict__ st,
                                                  u16* __restrict__ qrot) {
  __shared__ float Al[32 * 68];          // 8.7 KB
  int bid = blockIdx.x;                  // 512 blocks, 32 rows each
  int tid = threadIdx.x;
  int w = tid >> 6;
  int lane = tid & 63;
  int l15 = lane & 15;
  int quad = lane >> 4;
  int m0 = bid * 32;

  // coalesced staging: thread t loads 32 B of row (t>>3), cols (t&7)*8..+8
  int srow = tid >> 3;
  int sc8 = (tid & 7) * 8;
  const float* xg = x + (size_t)(m0 + srow) * CDIM + sc8;

  f32x4 acc[2][2];
#pragma unroll
  for (int mt = 0; mt < 2; ++mt)
#pragma unroll
    for (int nt = 0; nt < 2; ++nt) acc[mt][nt] = (f32x4){0.f, 0.f, 0.f, 0.f};

  float4 pa0 = *(const float4*)(xg);
  float4 pa1 = *(const float4*)(xg + 4);

  for (int it = 0; it < CDIM / 64; ++it) {   // 32 iterations, BK=64
    __syncthreads();
    *(float4*)&Al[srow * 68 + sc8] = pa0;
    *(float4*)&Al[srow * 68 + sc8 + 4] = pa1;
    __syncthreads();
    if (it + 1 < CDIM / 64) {
      const float* xn = xg + (size_t)(it + 1) * 64;
      pa0 = *(const float4*)(xn);
      pa1 = *(const float4*)(xn + 4);
    }
    int k0 = it * 64;
#pragma unroll
    for (int ks = 0; ks < 2; ++ks) {
      bf16x8 af[2];
#pragma unroll
      for (int mt = 0; mt < 2; ++mt) {
        const float* ap = &Al[(mt * 16 + l15) * 68 + ks * 32 + quad * 8];
        float4 f0 = *(const float4*)(ap);
        float4 f1 = *(const float4*)(ap + 4);
        af[mt] = cvt8(f0, f1);
      }
#pragma unroll
      for (int nt = 0; nt < 2; ++nt) {
        bf16x8 bfrag = ld_bf8(wbf + (size_t)(w * 32 + nt * 16 + l15) * CDIM + k0 + ks * 32 + quad * 8);
#pragma unroll
        for (int mt = 0; mt < 2; ++mt)
          acc[mt][nt] = __builtin_amdgcn_mfma_f32_16x16x32_bf16(af[mt], bfrag, acc[mt][nt], 0, 0, 0);
      }
    }
  }

  // epilogue: RoPE (pair exchange across even/odd lanes) + scale, store bf16
  const float scale = 0.08838834764831845f;  // 128^-0.5
#pragma unroll
  for (int mt = 0; mt < 2; ++mt)
#pragma unroll
    for (int nt = 0; nt < 2; ++nt) {
      int dcol = w * 32 + nt * 16 + l15;
      int p = dcol >> 1;
#pragma unroll
      for (int r = 0; r < 4; ++r) {
        int m = m0 + mt * 16 + quad * 4 + r;
        int t = m & (TSEQ - 1);
        float val = acc[mt][nt][r];
        float partner = __shfl_xor(val, 1, 64);
        float c = ct[t * 64 + p];
        float s = st[t * 64 + p];
        float o = (lane & 1) ? (val * c + partner * s) : (val * c - partner * s);
        qrot[(size_t)m * DH + dcol] = f2bf(o * scale);
      }
    }
}

// ------- causal flash attention: uniform work units (b, 64-row q-tile, <=16 k-tiles) -------
__global__ __launch_bounds__(256) void k_attn(const u16* __restrict__ qrot,
                                              const u16* __restrict__ krot,
                                              const u16* __restrict__ vt,
                                              u16* __restrict__ Opart,
                                              float2* __restrict__ ml) {
  __shared__ u16 Kl[16 * 64 * 8];
  __shared__ u16 Vl[8 * 128 * 8];
  __shared__ u16 Pl[4 * 16 * 72];

  int bid = blockIdx.x;              // 640 = 4 batches * 160 units
  int b = bid / 160;
  int u = bid - b * 160;
  int qt, kc;
  if (u < 16)      { qt = u;                kc = 0; }
  else if (u < 48) { qt = 16 + ((u - 16) >> 1); kc = (u - 16) & 1; }
  else if (u < 96) { int q3 = (u - 48) / 3; qt = 32 + q3; kc = (u - 48) - 3 * q3; }
  else             { qt = 48 + ((u - 96) >> 2); kc = (u - 96) & 3; }
  int kt0 = kc * 16;
  int kt1 = min(kt0 + 16, qt + 1);

  int tid = threadIdx.x;
  int w = tid >> 6;
  int lane = tid & 63;
  int l15 = lane & 15;
  int quad = lane >> 4;
  u16* pw = Pl + w * 16 * 72;

  int rK  = tid & 63;   int jgK = tid >> 6;
  int dV  = tid & 127;  int hV  = tid >> 7;

  const u16* kb = krot + (size_t)b * TSEQ * DH;
  const u16* vb = vt + (size_t)b * DH * TSEQ;

  bf16x8 qf[4];
  {
    const u16* qb = qrot + ((size_t)(b * TSEQ + qt * 64 + w * 16 + l15)) * DH + quad * 8;
#pragma unroll
    for (int c = 0; c < 4; ++c) qf[c] = ld_bf8(qb + c * 32);
  }

  f32x4 o_acc[8];
#pragma unroll
  for (int i = 0; i < 8; ++i) o_acc[i] = (f32x4){0.f, 0.f, 0.f, 0.f};
  float m_st[4], l_st[4];
#pragma unroll
  for (int r = 0; r < 4; ++r) { m_st[r] = -INFINITY; l_st[r] = 0.f; }

  u16x8 kr[4], vr[4];
  {
    const u16* ks = kb + (size_t)(kt0 * 64 + rK) * DH + jgK * 32;
    const u16* vs = vb + (size_t)dV * TSEQ + kt0 * 64 + hV * 32;
#pragma unroll
    for (int i = 0; i < 4; ++i) { kr[i] = *(const u16x8*)(ks + i * 8); vr[i] = *(const u16x8*)(vs + i * 8); }
  }

  for (int kt = kt0; kt < kt1; ++kt) {
    __syncthreads();
#pragma unroll
    for (int i = 0; i < 4; ++i) {
      *(u16x8*)&Kl[((jgK * 4 + i) * 64 + rK) * 8] = kr[i];
      *(u16x8*)&Vl[((hV * 4 + i) * 128 + dV) * 8] = vr[i];
    }
    __syncthreads();
    if (kt + 1 < kt1) {
      const u16* ks = kb + (size_t)((kt + 1) * 64 + rK) * DH + jgK * 32;
      const u16* vs = vb + (size_t)dV * TSEQ + (kt + 1) * 64 + hV * 32;
#pragma unroll
      for (int i = 0; i < 4; ++i) { kr[i] = *(const u16x8*)(ks + i * 8); vr[i] = *(const u16x8*)(vs + i * 8); }
    }

    f32x4 s[4];
#pragma unroll
    for (int nt = 0; nt < 4; ++nt) {
      s[nt] = (f32x4){0.f, 0.f, 0.f, 0.f};
#pragma unroll
      for (int c = 0; c < 4; ++c) {
        bf16x8 kf = ld_bf8(&Kl[((c * 4 + quad) * 64 + nt * 16 + l15) * 8]);
        s[nt] = __builtin_amdgcn_mfma_f32_16x16x32_bf16(qf[c], kf, s[nt], 0, 0, 0);
      }
    }
    if (kt == qt) {
#pragma unroll
      for (int nt = 0; nt < 4; ++nt)
#pragma unroll
        for (int r = 0; r < 4; ++r) {
          if (nt * 16 + l15 > w * 16 + quad * 4 + r) s[nt][r] = -INFINITY;
        }
    }
    float alpha[4];
#pragma unroll
    for (int r = 0; r < 4; ++r) {
      float rm = fmaxf(fmaxf(s[0][r], s[1][r]), fmaxf(s[2][r], s[3][r]));
      rm = red_max16(rm);
      float mn = fmaxf(m_st[r], rm);
      float al = __expf(m_st[r] - mn);
      m_st[r] = mn;
      float ps = 0.f;
#pragma unroll
      for (int nt = 0; nt < 4; ++nt) {
        float pv = __expf(s[nt][r] - mn);
        s[nt][r] = pv;
        ps += pv;
      }
      ps = red_sum16(ps);
      l_st[r] = l_st[r] * al + ps;
      alpha[r] = al;
    }
#pragma unroll
    for (int nt = 0; nt < 8; ++nt)
#pragma unroll
      for (int r = 0; r < 4; ++r) o_acc[nt][r] *= alpha[r];
#pragma unroll
    for (int nt = 0; nt < 4; ++nt)
#pragma unroll
      for (int r = 0; r < 4; ++r)
        pw[(quad * 4 + r) * 72 + nt * 16 + l15] = f2bf(s[nt][r]);
#pragma unroll
    for (int c2 = 0; c2 < 2; ++c2) {
      bf16x8 pf = ld_bf8(pw + l15 * 72 + c2 * 32 + quad * 8);
#pragma unroll
      for (int nt = 0; nt < 8; ++nt) {
        bf16x8 vf = ld_bf8(&Vl[((c2 * 4 + quad) * 128 + nt * 16 + l15) * 8]);
        o_acc[nt] = __builtin_amdgcn_mfma_f32_16x16x32_bf16(pf, vf, o_acc[nt], 0, 0, 0);
      }
    }
  }

  int slot = bid;
  u16* op = Opart + (size_t)slot * 8192;
#pragma unroll
  for (int nt = 0; nt < 8; ++nt)
#pragma unroll
    for (int r = 0; r < 4; ++r)
      op[(w * 16 + quad * 4 + r) * 128 + nt * 16 + l15] = f2bf(o_acc[nt][r]);
  if (l15 == 0) {
#pragma unroll
    for (int r = 0; r < 4; ++r) {
      float2 p; p.x = m_st[r]; p.y = l_st[r];
      ml[slot * 64 + w * 16 + quad * 4 + r] = p;
    }
  }
}

// ------- merge partials: one block per (b, 64-row q-tile) -------
__global__ __launch_bounds__(256) void k_merge(const u16* __restrict__ Opart,
                                               const float2* __restrict__ ml,
                                               float* __restrict__ out) {
  __shared__ float wgt[4][64];
  __shared__ float invL[64];
  int bid = blockIdx.x;
  int b = bid >> 6, qt = bid & 63;
  int C = 1 + (qt >> 4);
  int base = b * 160 + (qt < 16 ? qt
                       : qt < 32 ? 16 + 2 * (qt - 16)
                       : qt < 48 ? 48 + 3 * (qt - 32)
                       : 96 + 4 * (qt - 48));
  int tid = threadIdx.x;
  if (tid < 64) {
    float mv[4], lv[4];
    float M = -INFINITY;
    for (int uu = 0; uu < C; ++uu) {
      float2 p = ml[(base + uu) * 64 + tid];
      mv[uu] = p.x; lv[uu] = p.y;
      M = fmaxf(M, p.x);
    }
    float L = 0.f;
    for (int uu = 0; uu < C; ++uu) {
      float wv = __expf(mv[uu] - M);
      wgt[uu][tid] = wv;
      L += wv * lv[uu];
    }
    invL[tid] = 1.f / L;
  }
  __syncthreads();
#pragma unroll
  for (int k = 0; k < 32; ++k) {
    int e = tid + k * 256;
    int row = e >> 7;
    float acc = 0.f;
    for (int uu = 0; uu < C; ++uu)
      acc += wgt[uu][row] * bf2f(Opart[(size_t)(base + uu) * 8192 + e]);
    out[(size_t)(b * TSEQ + qt * 64) * DH + e] = acc * invL[row];
  }
}

extern "C" void kernel_launch(void* const* d_in, const int* in_sizes, int n_in,
                              void* d_out, int out_size, void* d_ws, size_t ws_size,
                              hipStream_t stream) {
  const float* x     = (const float*)d_in[0];
  const float* key   = (const float*)d_in[1];
  const float* value = (const float*)d_in[2];
  const float* w_q   = (const float*)d_in[3];
  float* out = (float*)d_out;

  char* ws = (char*)d_ws;
  u16* wbf    = (u16*)(ws);                                  // 512 KB
  u16* qrot   = (u16*)(ws + (512u << 10));                   // 4 MB
  u16* krot   = (u16*)(ws + (512u << 10) + (4u << 20));      // 4 MB
  u16* vt     = (u16*)(ws + (512u << 10) + (8u << 20));      // 4 MB
  float* ct   = (float*)(ws + (512u << 10) + (12u << 20));   // 1 MB
  float* st   = (float*)(ws + (512u << 10) + (13u << 20));   // 1 MB
  u16* Opart  = (u16*)(ws + (512u << 10) + (14u << 20));     // 10 MB
  float2* ml  = (float2*)(ws + (512u << 10) + (24u << 20));  // 320 KB

  k_trig<<<(TSEQ * 64) / 256, 256, 0, stream>>>(ct, st);
  k_wconv<<<256, 256, 0, stream>>>(w_q, wbf);
  k_ropek<<<(NBATCH * TSEQ * 64) / 256, 256, 0, stream>>>(key, ct, st, krot);
  k_vt<<<NBATCH * (TSEQ / 64), 256, 0, stream>>>(value, vt);
  k_qproj<<<(NBATCH * TSEQ) / 32, 256, 0, stream>>>(x, wbf, ct, st, qrot);
  k_attn<<<NBATCH * 160, 256, 0, stream>>>(qrot, krot, vt, Opart, ml);
  k_merge<<<NBATCH * 64, 256, 0, stream>>>(Opart, ml, out);
}

// Round 6
// 297.072 us; speedup vs baseline: 2.1981x; 1.1446x over previous
//
#include <hip/hip_runtime.h>
#include <hip/hip_bf16.h>

#define TSEQ  4096
#define NBATCH 4
#define CDIM  2048
#define DH    128

typedef __bf16 bf16x8 __attribute__((ext_vector_type(8)));
typedef float  f32x4  __attribute__((ext_vector_type(4)));
typedef unsigned short u16x8 __attribute__((ext_vector_type(8)));
typedef unsigned       u32x4 __attribute__((ext_vector_type(4)));
typedef unsigned short u16;

__device__ __forceinline__ u16 f2bf(float f) {
  union { float f; unsigned u; } v; v.f = f;
  unsigned r = (v.u + 0x7FFFu + ((v.u >> 16) & 1u)) >> 16;
  return (u16)r;
}
__device__ __forceinline__ float bf2f(u16 h) {
  union { unsigned u; float f; } v; v.u = ((unsigned)h) << 16;
  return v.f;
}
__device__ __forceinline__ bf16x8 ld_bf8(const u16* p) {
  return __builtin_bit_cast(bf16x8, *(const u16x8*)p);
}
__device__ __forceinline__ unsigned pk2(float lo, float hi) {
  float2 f; f.x = lo; f.y = hi;
  __hip_bfloat162 h = __float22bfloat162_rn(f);
  unsigned r; __builtin_memcpy(&r, &h, 4);
  return r;
}
__device__ __forceinline__ bf16x8 cvt8(float4 a, float4 b) {
  u32x4 u;
  u[0] = pk2(a.x, a.y); u[1] = pk2(a.z, a.w);
  u[2] = pk2(b.x, b.y); u[3] = pk2(b.z, b.w);
  return __builtin_bit_cast(bf16x8, u);
}

// DPP cross-lane (VALU pipe): reduce over each 16-lane row
template<int CTRL>
__device__ __forceinline__ float dppmv(float x) {
  return __builtin_bit_cast(float,
    __builtin_amdgcn_update_dpp(0, __builtin_bit_cast(int, x), CTRL, 0xF, 0xF, true));
}
__device__ __forceinline__ float red_max16(float v) {
  v = fmaxf(v, dppmv<0xB1>(v));
  v = fmaxf(v, dppmv<0x4E>(v));
  v = fmaxf(v, dppmv<0x124>(v));
  v = fmaxf(v, dppmv<0x128>(v));
  return v;
}
__device__ __forceinline__ float red_sum16(float v) {
  v += dppmv<0xB1>(v);
  v += dppmv<0x4E>(v);
  v += dppmv<0x124>(v);
  v += dppmv<0x128>(v);
  return v;
}

// unit base within a batch: q-tile Q (128 rows) has (Q>>2)+1 chunks
__device__ __forceinline__ int unit_base(int Q) {
  int a = Q >> 2, bq = Q & 3;
  return 2 * a * (a + 1) + bq * (a + 1);
}

// ---------------- fused prep: wconv | trig | ropek | vt in one launch ----------------
__global__ __launch_bounds__(256) void k_prep(const float* __restrict__ w, u16* __restrict__ wbf,
                                              const float* __restrict__ key, u16* __restrict__ krot,
                                              const float* __restrict__ value, u16* __restrict__ vt,
                                              float* __restrict__ ct, float* __restrict__ st) {
  __shared__ u16 S[128 * 66];
  int bid = blockIdx.x;
  int tid = threadIdx.x;
  if (bid < 256) {
    // w_q fp32 -> bf16 (262144 elems)
    int i = bid * 256 + tid;
    const float4 v = *(const float4*)(w + (size_t)i * 4);
    uint2 o; o.x = pk2(v.x, v.y); o.y = pk2(v.z, v.w);
    *(uint2*)(wbf + (size_t)i * 4) = o;
  } else if (bid < 1280) {
    // trig tables for qproj epilogue
    int i = (bid - 256) * 256 + tid;
    int p = i & 63;
    int t = i >> 6;
    float inv = powf(10000.0f, -(float)p / 64.0f);
    float ang = (float)t * inv;
    float s, c; sincosf(ang, &s, &c);
    ct[i] = c; st[i] = s;
  } else if (bid < 5376) {
    // rope(key) -> bf16, inline trig
    int g = (bid - 1280) * 256 + tid;
    int p = g & 63;
    int row = g >> 6;
    int t = row & (TSEQ - 1);
    const float2 kv = *(const float2*)(key + (size_t)row * DH + 2 * p);
    float inv = powf(10000.0f, -(float)p / 64.0f);
    float ang = (float)t * inv;
    float s, c; sincosf(ang, &s, &c);
    *(unsigned*)(krot + (size_t)row * DH + 2 * p) = pk2(kv.x * c - kv.y * s, kv.x * s + kv.y * c);
  } else {
    // transpose value -> bf16 v_t[b][d][t]
    int vb = bid - 5376;
    int b = vb >> 6;
    int t0 = (vb & 63) * 64;
    int d = (tid & 31) * 4;
    int tl0 = tid >> 5;
#pragma unroll
    for (int i = 0; i < 8; ++i) {
      int tl = tl0 + i * 8;
      const float4 val = *(const float4*)(value + ((size_t)(b * TSEQ + t0 + tl)) * DH + d);
      S[(d + 0) * 66 + tl] = f2bf(val.x);
      S[(d + 1) * 66 + tl] = f2bf(val.y);
      S[(d + 2) * 66 + tl] = f2bf(val.z);
      S[(d + 3) * 66 + tl] = f2bf(val.w);
    }
    __syncthreads();
#pragma unroll
    for (int i = 0; i < 16; ++i) {
      int idx = tid + i * 256;
      int dd = idx >> 5;
      int tw = (idx & 31) * 2;
      unsigned lo = S[dd * 66 + tw];
      unsigned hi = S[dd * 66 + tw + 1];
      *(unsigned*)(vt + ((size_t)(b * DH + dd)) * TSEQ + t0 + tw) = lo | (hi << 16);
    }
  }
}

// ------- q projection: LDS-staged GEMM, 32-row tiles, full-K per block, fused RoPE -------
__global__ __launch_bounds__(256, 2) void k_qproj(const float* __restrict__ x,
                                                  const u16* __restrict__ wbf,
                                                  const float* __restrict__ ct,
                                                  const float* __restrict__ st,
                                                  u16* __restrict__ qrot) {
  __shared__ float Al[32 * 68];
  int bid = blockIdx.x;
  int tid = threadIdx.x;
  int w = tid >> 6;
  int lane = tid & 63;
  int l15 = lane & 15;
  int quad = lane >> 4;
  int m0 = bid * 32;

  int srow = tid >> 3;
  int sc8 = (tid & 7) * 8;
  const float* xg = x + (size_t)(m0 + srow) * CDIM + sc8;

  f32x4 acc[2][2];
#pragma unroll
  for (int mt = 0; mt < 2; ++mt)
#pragma unroll
    for (int nt = 0; nt < 2; ++nt) acc[mt][nt] = (f32x4){0.f, 0.f, 0.f, 0.f};

  float4 pa0 = *(const float4*)(xg);
  float4 pa1 = *(const float4*)(xg + 4);

  for (int it = 0; it < CDIM / 64; ++it) {
    __syncthreads();
    *(float4*)&Al[srow * 68 + sc8] = pa0;
    *(float4*)&Al[srow * 68 + sc8 + 4] = pa1;
    __syncthreads();
    if (it + 1 < CDIM / 64) {
      const float* xn = xg + (size_t)(it + 1) * 64;
      pa0 = *(const float4*)(xn);
      pa1 = *(const float4*)(xn + 4);
    }
    int k0 = it * 64;
#pragma unroll
    for (int ks = 0; ks < 2; ++ks) {
      bf16x8 af[2];
#pragma unroll
      for (int mt = 0; mt < 2; ++mt) {
        const float* ap = &Al[(mt * 16 + l15) * 68 + ks * 32 + quad * 8];
        float4 f0 = *(const float4*)(ap);
        float4 f1 = *(const float4*)(ap + 4);
        af[mt] = cvt8(f0, f1);
      }
#pragma unroll
      for (int nt = 0; nt < 2; ++nt) {
        bf16x8 bfrag = ld_bf8(wbf + (size_t)(w * 32 + nt * 16 + l15) * CDIM + k0 + ks * 32 + quad * 8);
#pragma unroll
        for (int mt = 0; mt < 2; ++mt)
          acc[mt][nt] = __builtin_amdgcn_mfma_f32_16x16x32_bf16(af[mt], bfrag, acc[mt][nt], 0, 0, 0);
      }
    }
  }

  const float scale = 0.08838834764831845f;  // 128^-0.5
#pragma unroll
  for (int mt = 0; mt < 2; ++mt)
#pragma unroll
    for (int nt = 0; nt < 2; ++nt) {
      int dcol = w * 32 + nt * 16 + l15;
      int p = dcol >> 1;
#pragma unroll
      for (int r = 0; r < 4; ++r) {
        int m = m0 + mt * 16 + quad * 4 + r;
        int t = m & (TSEQ - 1);
        float val = acc[mt][nt][r];
        float partner = __shfl_xor(val, 1, 64);
        float c = ct[t * 64 + p];
        float s = st[t * 64 + p];
        float o = (lane & 1) ? (val * c + partner * s) : (val * c - partner * s);
        qrot[(size_t)m * DH + dcol] = f2bf(o * scale);
      }
    }
}

// ------- causal flash attention: units = (b, 128-row q-tile, <=8 k-tiles of 64 keys) -------
// 4 waves/block, each wave owns 32 q-rows (2 m-frags); K/V LDS-staged and shared by all
// waves -> 64 MFMA per 36 LDS-b128-reads per wave-tile. 576 uniform blocks.
__global__ __launch_bounds__(256, 2) void k_attn(const u16* __restrict__ qrot,
                                                 const u16* __restrict__ krot,
                                                 const u16* __restrict__ vt,
                                                 u16* __restrict__ Opart,
                                                 float2* __restrict__ ml) {
  __shared__ u16 Kl[16 * 64 * 8];      // 16 KB
  __shared__ u16 Vl[8 * 128 * 8];      // 16 KB
  __shared__ u16 Pl[4 * 32 * 72];      // 18 KB (per-wave 32 rows, stride 72)

  int bid = blockIdx.x;                // 576 = 4 * 144
  int b = bid / 144;
  int u = bid - b * 144;
  int Q = 0;
#pragma unroll 1
  for (int q = 31; q >= 0; --q) {
    if (unit_base(q) <= u) { Q = q; break; }
  }
  int kc = u - unit_base(Q);
  int nkt = 2 * Q + 2;
  int kt0 = kc * 8;
  int kt1 = min(kt0 + 8, nkt);
  int m0 = Q * 128;                    // first q-row of this tile (within batch)

  int tid = threadIdx.x;
  int w = tid >> 6;
  int lane = tid & 63;
  int l15 = lane & 15;
  int quad = lane >> 4;
  u16* pw = Pl + w * 32 * 72;

  int rK = tid & 63;   int jgK = tid >> 6;
  int dV = tid & 127;  int hV = tid >> 7;

  const u16* kb = krot + (size_t)b * TSEQ * DH;
  const u16* vb = vt + (size_t)b * DH * TSEQ;

  // Q fragments: wave w owns rows m0 + mt*64 + w*16 + (0..15)
  bf16x8 qf[2][4];
#pragma unroll
  for (int mt = 0; mt < 2; ++mt) {
    const u16* qb = qrot + ((size_t)(b * TSEQ + m0 + mt * 64 + w * 16 + l15)) * DH + quad * 8;
#pragma unroll
    for (int c = 0; c < 4; ++c) qf[mt][c] = ld_bf8(qb + c * 32);
  }

  f32x4 o_acc[2][8];
#pragma unroll
  for (int mt = 0; mt < 2; ++mt)
#pragma unroll
    for (int i = 0; i < 8; ++i) o_acc[mt][i] = (f32x4){0.f, 0.f, 0.f, 0.f};
  float m_st[2][4], l_st[2][4];
#pragma unroll
  for (int mt = 0; mt < 2; ++mt)
#pragma unroll
    for (int r = 0; r < 4; ++r) { m_st[mt][r] = -INFINITY; l_st[mt][r] = 0.f; }

  u16x8 kr[4], vr[4];
  {
    const u16* ks = kb + (size_t)(kt0 * 64 + rK) * DH + jgK * 32;
    const u16* vs = vb + (size_t)dV * TSEQ + kt0 * 64 + hV * 32;
#pragma unroll
    for (int i = 0; i < 4; ++i) { kr[i] = *(const u16x8*)(ks + i * 8); vr[i] = *(const u16x8*)(vs + i * 8); }
  }

  for (int kt = kt0; kt < kt1; ++kt) {
    __syncthreads();
#pragma unroll
    for (int i = 0; i < 4; ++i) {
      *(u16x8*)&Kl[((jgK * 4 + i) * 64 + rK) * 8] = kr[i];
      *(u16x8*)&Vl[((hV * 4 + i) * 128 + dV) * 8] = vr[i];
    }
    __syncthreads();
    if (kt + 1 < kt1) {
      const u16* ks = kb + (size_t)((kt + 1) * 64 + rK) * DH + jgK * 32;
      const u16* vs = vb + (size_t)dV * TSEQ + (kt + 1) * 64 + hV * 32;
#pragma unroll
      for (int i = 0; i < 4; ++i) { kr[i] = *(const u16x8*)(ks + i * 8); vr[i] = *(const u16x8*)(vs + i * 8); }
    }

    // S = Q @ K^T : 2 m-frags x 4 key-frags, K-frag loaded once, reused across mt
    f32x4 s[2][4];
#pragma unroll
    for (int mt = 0; mt < 2; ++mt)
#pragma unroll
      for (int nt = 0; nt < 4; ++nt) s[mt][nt] = (f32x4){0.f, 0.f, 0.f, 0.f};
#pragma unroll
    for (int c = 0; c < 4; ++c)
#pragma unroll
      for (int nt = 0; nt < 4; ++nt) {
        bf16x8 kf = ld_bf8(&Kl[((c * 4 + quad) * 64 + nt * 16 + l15) * 8]);
#pragma unroll
        for (int mt = 0; mt < 2; ++mt)
          s[mt][nt] = __builtin_amdgcn_mfma_f32_16x16x32_bf16(qf[mt][c], kf, s[mt][nt], 0, 0, 0);
      }

    // causal mask (only tiles at/after the diagonal band)
    if (kt * 64 >= m0) {
#pragma unroll
      for (int mt = 0; mt < 2; ++mt)
#pragma unroll
        for (int nt = 0; nt < 4; ++nt)
#pragma unroll
          for (int r = 0; r < 4; ++r) {
            int key_g = kt * 64 + nt * 16 + l15;
            int row_g = m0 + mt * 64 + w * 16 + quad * 4 + r;
            if (key_g > row_g) s[mt][nt][r] = -INFINITY;
          }
    }

    // online softmax per row (8 rows/wave), DPP reductions
    float alpha[2][4];
    int chg = 0;
#pragma unroll
    for (int mt = 0; mt < 2; ++mt)
#pragma unroll
      for (int r = 0; r < 4; ++r) {
        float rm = fmaxf(fmaxf(s[mt][0][r], s[mt][1][r]), fmaxf(s[mt][2][r], s[mt][3][r]));
        rm = red_max16(rm);
        float mn = fmaxf(m_st[mt][r], rm);
        float al = __expf(m_st[mt][r] - mn);
        m_st[mt][r] = mn;
        float ps = 0.f;
#pragma unroll
        for (int nt = 0; nt < 4; ++nt) {
          float pv = __expf(s[mt][nt][r] - mn);
          s[mt][nt][r] = pv;
          ps += pv;
        }
        ps = red_sum16(ps);
        l_st[mt][r] = l_st[mt][r] * al + ps;
        alpha[mt][r] = al;
        chg |= (al != 1.0f);
      }
    if (__any(chg)) {
#pragma unroll
      for (int mt = 0; mt < 2; ++mt)
#pragma unroll
        for (int nt = 0; nt < 8; ++nt)
#pragma unroll
          for (int r = 0; r < 4; ++r) o_acc[mt][nt][r] *= alpha[mt][r];
    }

    // P: C-layout -> per-wave LDS -> A-layout
#pragma unroll
    for (int mt = 0; mt < 2; ++mt)
#pragma unroll
      for (int nt = 0; nt < 4; ++nt)
#pragma unroll
        for (int r = 0; r < 4; ++r)
          pw[(mt * 16 + quad * 4 + r) * 72 + nt * 16 + l15] = f2bf(s[mt][nt][r]);

    // O += P @ V : V-frag loaded once, reused across mt
#pragma unroll
    for (int c2 = 0; c2 < 2; ++c2) {
      bf16x8 pf[2];
#pragma unroll
      for (int mt = 0; mt < 2; ++mt)
        pf[mt] = ld_bf8(pw + (mt * 16 + l15) * 72 + c2 * 32 + quad * 8);
#pragma unroll
      for (int nt = 0; nt < 8; ++nt) {
        bf16x8 vf = ld_bf8(&Vl[((c2 * 4 + quad) * 128 + nt * 16 + l15) * 8]);
#pragma unroll
        for (int mt = 0; mt < 2; ++mt)
          o_acc[mt][nt] = __builtin_amdgcn_mfma_f32_16x16x32_bf16(pf[mt], vf, o_acc[mt][nt], 0, 0, 0);
      }
    }
  }

  // epilogue: unnormalized bf16 partial + (m,l)
  u16* op = Opart + (size_t)bid * (128 * 128);
#pragma unroll
  for (int mt = 0; mt < 2; ++mt)
#pragma unroll
    for (int nt = 0; nt < 8; ++nt)
#pragma unroll
      for (int r = 0; r < 4; ++r)
        op[(mt * 64 + w * 16 + quad * 4 + r) * 128 + nt * 16 + l15] = f2bf(o_acc[mt][nt][r]);
  if (l15 == 0) {
#pragma unroll
    for (int mt = 0; mt < 2; ++mt)
#pragma unroll
      for (int r = 0; r < 4; ++r) {
        float2 p; p.x = m_st[mt][r]; p.y = l_st[mt][r];
        ml[(size_t)bid * 128 + mt * 64 + w * 16 + quad * 4 + r] = p;
      }
  }
}

// ------- merge partials: one block per (b, 128-row q-tile), vectorized -------
__global__ __launch_bounds__(256) void k_merge(const u16* __restrict__ Opart,
                                               const float2* __restrict__ ml,
                                               float* __restrict__ out) {
  __shared__ float wgt[8][128];
  __shared__ float invL[128];
  int bid = blockIdx.x;                // b*32 + Q
  int b = bid >> 5, Q = bid & 31;
  int C = (Q >> 2) + 1;
  int base = b * 144 + unit_base(Q);
  int tid = threadIdx.x;
  if (tid < 128) {
    float mv[8], lv[8];
    float M = -INFINITY;
    for (int c = 0; c < C; ++c) {
      float2 p = ml[(size_t)(base + c) * 128 + tid];
      mv[c] = p.x; lv[c] = p.y;
      M = fmaxf(M, p.x);
    }
    float L = 0.f;
    for (int c = 0; c < C; ++c) {
      float wv = __expf(mv[c] - M);
      wgt[c][tid] = wv;
      L += wv * lv[c];
    }
    invL[tid] = 1.f / L;
  }
  __syncthreads();
#pragma unroll
  for (int k = 0; k < 8; ++k) {
    int slot = tid + k * 256;          // 2048 slots of 8 elems (128x128)
    int row = slot >> 4;
    float acc[8];
#pragma unroll
    for (int j = 0; j < 8; ++j) acc[j] = 0.f;
    for (int c = 0; c < C; ++c) {
      u16x8 v = *(const u16x8*)&Opart[(size_t)(base + c) * (128 * 128) + slot * 8];
      float wv = wgt[c][row];
#pragma unroll
      for (int j = 0; j < 8; ++j) acc[j] += wv * bf2f(v[j]);
    }
    float il = invL[row];
    float4 o0, o1;
    o0.x = acc[0] * il; o0.y = acc[1] * il; o0.z = acc[2] * il; o0.w = acc[3] * il;
    o1.x = acc[4] * il; o1.y = acc[5] * il; o1.z = acc[6] * il; o1.w = acc[7] * il;
    float* op = out + ((size_t)(b * TSEQ + Q * 128 + row)) * DH + (slot & 15) * 8;
    *(float4*)op = o0;
    *(float4*)(op + 4) = o1;
  }
}

extern "C" void kernel_launch(void* const* d_in, const int* in_sizes, int n_in,
                              void* d_out, int out_size, void* d_ws, size_t ws_size,
                              hipStream_t stream) {
  const float* x     = (const float*)d_in[0];
  const float* key   = (const float*)d_in[1];
  const float* value = (const float*)d_in[2];
  const float* w_q   = (const float*)d_in[3];
  float* out = (float*)d_out;

  // workspace layout (~34.5 MB)
  char* ws = (char*)d_ws;
  u16* wbf    = (u16*)(ws);                                  // 512 KB
  u16* qrot   = (u16*)(ws + (512u << 10));                   // 4 MB
  u16* krot   = (u16*)(ws + (512u << 10) + (4u << 20));      // 4 MB
  u16* vt     = (u16*)(ws + (512u << 10) + (8u << 20));      // 4 MB
  float* ct   = (float*)(ws + (512u << 10) + (12u << 20));   // 1 MB
  float* st   = (float*)(ws + (512u << 10) + (13u << 20));   // 1 MB
  u16* Opart  = (u16*)(ws + (512u << 10) + (14u << 20));     // 576*32KB = 18.87 MB
  float2* ml  = (float2*)(ws + (512u << 10) + (34u << 20));  // 576*128*8 = 590 KB

  k_prep<<<5632, 256, 0, stream>>>(w_q, wbf, key, krot, value, vt, ct, st);
  k_qproj<<<(NBATCH * TSEQ) / 32, 256, 0, stream>>>(x, wbf, ct, st, qrot);
  k_attn<<<NBATCH * 144, 256, 0, stream>>>(qrot, krot, vt, Opart, ml);
  k_merge<<<NBATCH * 32, 256, 0, stream>>>(Opart, ml, out);
}

// Round 7
// 291.272 us; speedup vs baseline: 2.2418x; 1.0199x over previous
//
#include <hip/hip_runtime.h>
#include <hip/hip_bf16.h>

#define TSEQ  4096
#define NBATCH 4
#define CDIM  2048
#define DH    128

typedef __bf16 bf16x8 __attribute__((ext_vector_type(8)));
typedef float  f32x4  __attribute__((ext_vector_type(4)));
typedef unsigned short u16x8 __attribute__((ext_vector_type(8)));
typedef unsigned       u32x4 __attribute__((ext_vector_type(4)));
typedef unsigned short u16;

__device__ __forceinline__ u16 f2bf(float f) {
  union { float f; unsigned u; } v; v.f = f;
  unsigned r = (v.u + 0x7FFFu + ((v.u >> 16) & 1u)) >> 16;
  return (u16)r;
}
__device__ __forceinline__ float bf2f(u16 h) {
  union { unsigned u; float f; } v; v.u = ((unsigned)h) << 16;
  return v.f;
}
__device__ __forceinline__ bf16x8 ld_bf8(const u16* p) {
  return __builtin_bit_cast(bf16x8, *(const u16x8*)p);
}
__device__ __forceinline__ unsigned pk2(float lo, float hi) {
  float2 f; f.x = lo; f.y = hi;
  __hip_bfloat162 h = __float22bfloat162_rn(f);
  unsigned r; __builtin_memcpy(&r, &h, 4);
  return r;
}
__device__ __forceinline__ u16x8 cvt8u(float4 a, float4 b) {
  u32x4 u;
  u[0] = pk2(a.x, a.y); u[1] = pk2(a.z, a.w);
  u[2] = pk2(b.x, b.y); u[3] = pk2(b.z, b.w);
  return __builtin_bit_cast(u16x8, u);
}

// DPP cross-lane (VALU pipe): reduce over each 16-lane row
template<int CTRL>
__device__ __forceinline__ float dppmv(float x) {
  return __builtin_bit_cast(float,
    __builtin_amdgcn_update_dpp(0, __builtin_bit_cast(int, x), CTRL, 0xF, 0xF, true));
}
__device__ __forceinline__ float red_max16(float v) {
  v = fmaxf(v, dppmv<0xB1>(v));
  v = fmaxf(v, dppmv<0x4E>(v));
  v = fmaxf(v, dppmv<0x124>(v));
  v = fmaxf(v, dppmv<0x128>(v));
  return v;
}
__device__ __forceinline__ float red_sum16(float v) {
  v += dppmv<0xB1>(v);
  v += dppmv<0x4E>(v);
  v += dppmv<0x124>(v);
  v += dppmv<0x128>(v);
  return v;
}

// unit base within a batch: q-tile Q (128 rows) has (Q>>2)+1 chunks
__device__ __forceinline__ int unit_base(int Q) {
  int a = Q >> 2, bq = Q & 3;
  return 2 * a * (a + 1) + bq * (a + 1);
}

// ---------------- fused prep: wconv | trig | ropek | vt in one launch ----------------
__global__ __launch_bounds__(256) void k_prep(const float* __restrict__ w, u16* __restrict__ wbf,
                                              const float* __restrict__ key, u16* __restrict__ krot,
                                              const float* __restrict__ value, u16* __restrict__ vt,
                                              float* __restrict__ ct, float* __restrict__ st) {
  __shared__ u16 S[128 * 66];
  int bid = blockIdx.x;
  int tid = threadIdx.x;
  if (bid < 256) {
    int i = bid * 256 + tid;
    const float4 v = *(const float4*)(w + (size_t)i * 4);
    uint2 o; o.x = pk2(v.x, v.y); o.y = pk2(v.z, v.w);
    *(uint2*)(wbf + (size_t)i * 4) = o;
  } else if (bid < 1280) {
    int i = (bid - 256) * 256 + tid;
    int p = i & 63;
    int t = i >> 6;
    float inv = powf(10000.0f, -(float)p / 64.0f);
    float ang = (float)t * inv;
    float s, c; sincosf(ang, &s, &c);
    ct[i] = c; st[i] = s;
  } else if (bid < 5376) {
    int g = (bid - 1280) * 256 + tid;
    int p = g & 63;
    int row = g >> 6;
    int t = row & (TSEQ - 1);
    const float2 kv = *(const float2*)(key + (size_t)row * DH + 2 * p);
    float inv = powf(10000.0f, -(float)p / 64.0f);
    float ang = (float)t * inv;
    float s, c; sincosf(ang, &s, &c);
    *(unsigned*)(krot + (size_t)row * DH + 2 * p) = pk2(kv.x * c - kv.y * s, kv.x * s + kv.y * c);
  } else {
    int vb = bid - 5376;
    int b = vb >> 6;
    int t0 = (vb & 63) * 64;
    int d = (tid & 31) * 4;
    int tl0 = tid >> 5;
#pragma unroll
    for (int i = 0; i < 8; ++i) {
      int tl = tl0 + i * 8;
      const float4 val = *(const float4*)(value + ((size_t)(b * TSEQ + t0 + tl)) * DH + d);
      S[(d + 0) * 66 + tl] = f2bf(val.x);
      S[(d + 1) * 66 + tl] = f2bf(val.y);
      S[(d + 2) * 66 + tl] = f2bf(val.z);
      S[(d + 3) * 66 + tl] = f2bf(val.w);
    }
    __syncthreads();
#pragma unroll
    for (int i = 0; i < 16; ++i) {
      int idx = tid + i * 256;
      int dd = idx >> 5;
      int tw = (idx & 31) * 2;
      unsigned lo = S[dd * 66 + tw];
      unsigned hi = S[dd * 66 + tw + 1];
      *(unsigned*)(vt + ((size_t)(b * DH + dd)) * TSEQ + t0 + tw) = lo | (hi << 16);
    }
  }
}

// ------- q projection: bf16 frag-major LDS tile, BK=128, 32-row tiles, fused RoPE -------
// 512 blocks (2/CU). Thread t loads 64 B of x (row t>>3, col chunk (t&7)*16), converts
// to bf16 in registers, stages frag-major [chunk16][row32][8] (uniform bank use), then
// 16 MFMA/wave/iter. 16 iterations, 2-barrier prefetch pipeline.
__global__ __launch_bounds__(256, 2) void k_qproj(const float* __restrict__ x,
                                                  const u16* __restrict__ wbf,
                                                  const float* __restrict__ ct,
                                                  const float* __restrict__ st,
                                                  u16* __restrict__ qrot) {
  __shared__ u16 Al[16 * 32 * 8];        // 8 KB, [chunk][row][8]
  int bid = blockIdx.x;
  int tid = threadIdx.x;
  int w = tid >> 6;
  int lane = tid & 63;
  int l15 = lane & 15;
  int quad = lane >> 4;
  int m0 = bid * 32;

  int srow = tid >> 3;                   // 0..31
  int c16 = (tid & 7) * 16;              // col offset 0..112
  int chunk0 = (tid & 7) * 2;
  const float* xg = x + (size_t)(m0 + srow) * CDIM + c16;

  f32x4 acc[2][2];
#pragma unroll
  for (int mt = 0; mt < 2; ++mt)
#pragma unroll
    for (int nt = 0; nt < 2; ++nt) acc[mt][nt] = (f32x4){0.f, 0.f, 0.f, 0.f};

  float4 pa[4];
#pragma unroll
  for (int i = 0; i < 4; ++i) pa[i] = *(const float4*)(xg + i * 4);

  for (int it = 0; it < CDIM / 128; ++it) {   // 16 iterations, BK=128
    u16x8 lo = cvt8u(pa[0], pa[1]);
    u16x8 hi = cvt8u(pa[2], pa[3]);
    __syncthreads();
    *(u16x8*)&Al[(chunk0 * 32 + srow) * 8] = lo;
    *(u16x8*)&Al[((chunk0 + 1) * 32 + srow) * 8] = hi;
    __syncthreads();
    if (it + 1 < CDIM / 128) {
      const float* xn = xg + (size_t)(it + 1) * 128;
#pragma unroll
      for (int i = 0; i < 4; ++i) pa[i] = *(const float4*)(xn + i * 4);
    }
    int k0 = it * 128;
#pragma unroll
    for (int ks = 0; ks < 4; ++ks) {
      bf16x8 af[2];
#pragma unroll
      for (int mt = 0; mt < 2; ++mt)
        af[mt] = ld_bf8(&Al[(((ks * 4 + quad) * 32) + mt * 16 + l15) * 8]);
#pragma unroll
      for (int nt = 0; nt < 2; ++nt) {
        bf16x8 bfrag = ld_bf8(wbf + (size_t)(w * 32 + nt * 16 + l15) * CDIM + k0 + ks * 32 + quad * 8);
#pragma unroll
        for (int mt = 0; mt < 2; ++mt)
          acc[mt][nt] = __builtin_amdgcn_mfma_f32_16x16x32_bf16(af[mt], bfrag, acc[mt][nt], 0, 0, 0);
      }
    }
  }

  const float scale = 0.08838834764831845f;  // 128^-0.5
#pragma unroll
  for (int mt = 0; mt < 2; ++mt)
#pragma unroll
    for (int nt = 0; nt < 2; ++nt) {
      int dcol = w * 32 + nt * 16 + l15;
      int p = dcol >> 1;
#pragma unroll
      for (int r = 0; r < 4; ++r) {
        int m = m0 + mt * 16 + quad * 4 + r;
        int t = m & (TSEQ - 1);
        float val = acc[mt][nt][r];
        float partner = __shfl_xor(val, 1, 64);
        float c = ct[t * 64 + p];
        float s = st[t * 64 + p];
        float o = (lane & 1) ? (val * c + partner * s) : (val * c - partner * s);
        qrot[(size_t)m * DH + dcol] = f2bf(o * scale);
      }
    }
}

// ------- causal flash attention: units = (b, 128-row q-tile, <=8 k-tiles of 64 keys) -------
__global__ __launch_bounds__(256, 2) void k_attn(const u16* __restrict__ qrot,
                                                 const u16* __restrict__ krot,
                                                 const u16* __restrict__ vt,
                                                 u16* __restrict__ Opart,
                                                 float2* __restrict__ ml) {
  __shared__ u16 Kl[16 * 64 * 8];
  __shared__ u16 Vl[8 * 128 * 8];
  __shared__ u16 Pl[4 * 32 * 72];

  int bid = blockIdx.x;                // 576 = 4 * 144
  int b = bid / 144;
  int u = bid - b * 144;
  int Q = 0;
#pragma unroll 1
  for (int q = 31; q >= 0; --q) {
    if (unit_base(q) <= u) { Q = q; break; }
  }
  int kc = u - unit_base(Q);
  int nkt = 2 * Q + 2;
  int kt0 = kc * 8;
  int kt1 = min(kt0 + 8, nkt);
  int m0 = Q * 128;

  int tid = threadIdx.x;
  int w = tid >> 6;
  int lane = tid & 63;
  int l15 = lane & 15;
  int quad = lane >> 4;
  u16* pw = Pl + w * 32 * 72;

  int rK = tid & 63;   int jgK = tid >> 6;
  int dV = tid & 127;  int hV = tid >> 7;

  const u16* kb = krot + (size_t)b * TSEQ * DH;
  const u16* vb = vt + (size_t)b * DH * TSEQ;

  bf16x8 qf[2][4];
#pragma unroll
  for (int mt = 0; mt < 2; ++mt) {
    const u16* qb = qrot + ((size_t)(b * TSEQ + m0 + mt * 64 + w * 16 + l15)) * DH + quad * 8;
#pragma unroll
    for (int c = 0; c < 4; ++c) qf[mt][c] = ld_bf8(qb + c * 32);
  }

  f32x4 o_acc[2][8];
#pragma unroll
  for (int mt = 0; mt < 2; ++mt)
#pragma unroll
    for (int i = 0; i < 8; ++i) o_acc[mt][i] = (f32x4){0.f, 0.f, 0.f, 0.f};
  float m_st[2][4], l_st[2][4];
#pragma unroll
  for (int mt = 0; mt < 2; ++mt)
#pragma unroll
    for (int r = 0; r < 4; ++r) { m_st[mt][r] = -INFINITY; l_st[mt][r] = 0.f; }

  u16x8 kr[4], vr[4];
  {
    const u16* ks = kb + (size_t)(kt0 * 64 + rK) * DH + jgK * 32;
    const u16* vs = vb + (size_t)dV * TSEQ + kt0 * 64 + hV * 32;
#pragma unroll
    for (int i = 0; i < 4; ++i) { kr[i] = *(const u16x8*)(ks + i * 8); vr[i] = *(const u16x8*)(vs + i * 8); }
  }

  for (int kt = kt0; kt < kt1; ++kt) {
    __syncthreads();
#pragma unroll
    for (int i = 0; i < 4; ++i) {
      *(u16x8*)&Kl[((jgK * 4 + i) * 64 + rK) * 8] = kr[i];
      *(u16x8*)&Vl[((hV * 4 + i) * 128 + dV) * 8] = vr[i];
    }
    __syncthreads();
    if (kt + 1 < kt1) {
      const u16* ks = kb + (size_t)((kt + 1) * 64 + rK) * DH + jgK * 32;
      const u16* vs = vb + (size_t)dV * TSEQ + (kt + 1) * 64 + hV * 32;
#pragma unroll
      for (int i = 0; i < 4; ++i) { kr[i] = *(const u16x8*)(ks + i * 8); vr[i] = *(const u16x8*)(vs + i * 8); }
    }

    f32x4 s[2][4];
#pragma unroll
    for (int mt = 0; mt < 2; ++mt)
#pragma unroll
      for (int nt = 0; nt < 4; ++nt) s[mt][nt] = (f32x4){0.f, 0.f, 0.f, 0.f};
#pragma unroll
    for (int c = 0; c < 4; ++c)
#pragma unroll
      for (int nt = 0; nt < 4; ++nt) {
        bf16x8 kf = ld_bf8(&Kl[((c * 4 + quad) * 64 + nt * 16 + l15) * 8]);
#pragma unroll
        for (int mt = 0; mt < 2; ++mt)
          s[mt][nt] = __builtin_amdgcn_mfma_f32_16x16x32_bf16(qf[mt][c], kf, s[mt][nt], 0, 0, 0);
      }

    if (kt * 64 >= m0) {
#pragma unroll
      for (int mt = 0; mt < 2; ++mt)
#pragma unroll
        for (int nt = 0; nt < 4; ++nt)
#pragma unroll
          for (int r = 0; r < 4; ++r) {
            int key_g = kt * 64 + nt * 16 + l15;
            int row_g = m0 + mt * 64 + w * 16 + quad * 4 + r;
            if (key_g > row_g) s[mt][nt][r] = -INFINITY;
          }
    }

    float alpha[2][4];
    int chg = 0;
#pragma unroll
    for (int mt = 0; mt < 2; ++mt)
#pragma unroll
      for (int r = 0; r < 4; ++r) {
        float rm = fmaxf(fmaxf(s[mt][0][r], s[mt][1][r]), fmaxf(s[mt][2][r], s[mt][3][r]));
        rm = red_max16(rm);
        float mn = fmaxf(m_st[mt][r], rm);
        float al = __expf(m_st[mt][r] - mn);
        m_st[mt][r] = mn;
        float ps = 0.f;
#pragma unroll
        for (int nt = 0; nt < 4; ++nt) {
          float pv = __expf(s[mt][nt][r] - mn);
          s[mt][nt][r] = pv;
          ps += pv;
        }
        ps = red_sum16(ps);
        l_st[mt][r] = l_st[mt][r] * al + ps;
        alpha[mt][r] = al;
        chg |= (al != 1.0f);
      }
    if (__any(chg)) {
#pragma unroll
      for (int mt = 0; mt < 2; ++mt)
#pragma unroll
        for (int nt = 0; nt < 8; ++nt)
#pragma unroll
          for (int r = 0; r < 4; ++r) o_acc[mt][nt][r] *= alpha[mt][r];
    }

#pragma unroll
    for (int mt = 0; mt < 2; ++mt)
#pragma unroll
      for (int nt = 0; nt < 4; ++nt)
#pragma unroll
        for (int r = 0; r < 4; ++r)
          pw[(mt * 16 + quad * 4 + r) * 72 + nt * 16 + l15] = f2bf(s[mt][nt][r]);

#pragma unroll
    for (int c2 = 0; c2 < 2; ++c2) {
      bf16x8 pf[2];
#pragma unroll
      for (int mt = 0; mt < 2; ++mt)
        pf[mt] = ld_bf8(pw + (mt * 16 + l15) * 72 + c2 * 32 + quad * 8);
#pragma unroll
      for (int nt = 0; nt < 8; ++nt) {
        bf16x8 vf = ld_bf8(&Vl[((c2 * 4 + quad) * 128 + nt * 16 + l15) * 8]);
#pragma unroll
        for (int mt = 0; mt < 2; ++mt)
          o_acc[mt][nt] = __builtin_amdgcn_mfma_f32_16x16x32_bf16(pf[mt], vf, o_acc[mt][nt], 0, 0, 0);
      }
    }
  }

  u16* op = Opart + (size_t)bid * (128 * 128);
#pragma unroll
  for (int mt = 0; mt < 2; ++mt)
#pragma unroll
    for (int nt = 0; nt < 8; ++nt)
#pragma unroll
      for (int r = 0; r < 4; ++r)
        op[(mt * 64 + w * 16 + quad * 4 + r) * 128 + nt * 16 + l15] = f2bf(o_acc[mt][nt][r]);
  if (l15 == 0) {
#pragma unroll
    for (int mt = 0; mt < 2; ++mt)
#pragma unroll
      for (int r = 0; r < 4; ++r) {
        float2 p; p.x = m_st[mt][r]; p.y = l_st[mt][r];
        ml[(size_t)bid * 128 + mt * 64 + w * 16 + quad * 4 + r] = p;
      }
  }
}

// ------- merge partials: one block per (b, 128-row q-tile), vectorized -------
__global__ __launch_bounds__(256) void k_merge(const u16* __restrict__ Opart,
                                               const float2* __restrict__ ml,
                                               float* __restrict__ out) {
  __shared__ float wgt[8][128];
  __shared__ float invL[128];
  int bid = blockIdx.x;                // b*32 + Q
  int b = bid >> 5, Q = bid & 31;
  int C = (Q >> 2) + 1;
  int base = b * 144 + unit_base(Q);
  int tid = threadIdx.x;
  if (tid < 128) {
    float mv[8], lv[8];
    float M = -INFINITY;
    for (int c = 0; c < C; ++c) {
      float2 p = ml[(size_t)(base + c) * 128 + tid];
      mv[c] = p.x; lv[c] = p.y;
      M = fmaxf(M, p.x);
    }
    float L = 0.f;
    for (int c = 0; c < C; ++c) {
      float wv = __expf(mv[c] - M);
      wgt[c][tid] = wv;
      L += wv * lv[c];
    }
    invL[tid] = 1.f / L;
  }
  __syncthreads();
#pragma unroll
  for (int k = 0; k < 8; ++k) {
    int slot = tid + k * 256;          // 2048 slots of 8 elems (128x128)
    int row = slot >> 4;
    float acc[8];
#pragma unroll
    for (int j = 0; j < 8; ++j) acc[j] = 0.f;
    for (int c = 0; c < C; ++c) {
      u16x8 v = *(const u16x8*)&Opart[(size_t)(base + c) * (128 * 128) + slot * 8];
      float wv = wgt[c][row];
#pragma unroll
      for (int j = 0; j < 8; ++j) acc[j] += wv * bf2f(v[j]);
    }
    float il = invL[row];
    float4 o0, o1;
    o0.x = acc[0] * il; o0.y = acc[1] * il; o0.z = acc[2] * il; o0.w = acc[3] * il;
    o1.x = acc[4] * il; o1.y = acc[5] * il; o1.z = acc[6] * il; o1.w = acc[7] * il;
    float* op = out + ((size_t)(b * TSEQ + Q * 128 + row)) * DH + (slot & 15) * 8;
    *(float4*)op = o0;
    *(float4*)(op + 4) = o1;
  }
}

extern "C" void kernel_launch(void* const* d_in, const int* in_sizes, int n_in,
                              void* d_out, int out_size, void* d_ws, size_t ws_size,
                              hipStream_t stream) {
  const float* x     = (const float*)d_in[0];
  const float* key   = (const float*)d_in[1];
  const float* value = (const float*)d_in[2];
  const float* w_q   = (const float*)d_in[3];
  float* out = (float*)d_out;

  char* ws = (char*)d_ws;
  u16* wbf    = (u16*)(ws);                                  // 512 KB
  u16* qrot   = (u16*)(ws + (512u << 10));                   // 4 MB
  u16* krot   = (u16*)(ws + (512u << 10) + (4u << 20));      // 4 MB
  u16* vt     = (u16*)(ws + (512u << 10) + (8u << 20));      // 4 MB
  float* ct   = (float*)(ws + (512u << 10) + (12u << 20));   // 1 MB
  float* st   = (float*)(ws + (512u << 10) + (13u << 20));   // 1 MB
  u16* Opart  = (u16*)(ws + (512u << 10) + (14u << 20));     // 18.87 MB
  float2* ml  = (float2*)(ws + (512u << 10) + (34u << 20));  // 590 KB

  k_prep<<<5632, 256, 0, stream>>>(w_q, wbf, key, krot, value, vt, ct, st);
  k_qproj<<<(NBATCH * TSEQ) / 32, 256, 0, stream>>>(x, wbf, ct, st, qrot);
  k_attn<<<NBATCH * 144, 256, 0, stream>>>(qrot, krot, vt, Opart, ml);
  k_merge<<<NBATCH * 32, 256, 0, stream>>>(Opart, ml, out);
}